// Round 1
// 853.683 us; speedup vs baseline: 1.0037x; 1.0037x over previous
//
#include <hip/hip_runtime.h>
#include <hip/hip_bf16.h>

#define B_ 16
#define N_ 1024
#define C_ 768
#define H_ 12
#define HD_ 64
#define QC_ (3*C_)      // 2304

using bf16 = __hip_bfloat16;
using bf16x8 = __attribute__((ext_vector_type(8))) __bf16;
using f32x4  = __attribute__((ext_vector_type(4))) float;

__device__ __forceinline__ float tof(bf16 v){ return __bfloat162float(v); }

// ---------------------------------------------------------------------------
// Input-dtype detector (1=bf16, 0=fp32) from bits 14:7 of sampled words.
// ---------------------------------------------------------------------------
__global__ __launch_bounds__(256) void detect_dtype(
    const unsigned* __restrict__ x32, int* __restrict__ flag)
{
  __shared__ int cnt;
  if (threadIdx.x == 0) cnt = 0;
  __syncthreads();
  int local = 0;
  #pragma unroll
  for (int i = 0; i < 16; i++) {
    unsigned u = x32[threadIdx.x * 16 + i * 4096];
    unsigned e = (u >> 7) & 0xFF;
    local += (e >= 110 && e <= 140) ? 1 : 0;
  }
  atomicAdd(&cnt, local);
  __syncthreads();
  if (threadIdx.x == 0) *flag = (cnt > 2048) ? 1 : 0;
}

// ---------------------------------------------------------------------------
// Cast x (fp32 or bf16 per flag) -> bf16, 4 elems/thread.
// ---------------------------------------------------------------------------
__global__ __launch_bounds__(256) void cvt_x(
    const void* __restrict__ x, bf16* __restrict__ xb,
    const int* __restrict__ flag, const int n4, const int off4)
{
  const int i = blockIdx.x * 256 + threadIdx.x;
  if (i >= n4) return;
  if (*flag) {
    ((uint2*)xb)[i] = ((const uint2*)x)[off4 + i];
  } else {
    float4 v = ((const float4*)x)[off4 + i];
    xb[i*4+0] = __float2bfloat16(v.x);
    xb[i*4+1] = __float2bfloat16(v.y);
    xb[i*4+2] = __float2bfloat16(v.z);
    xb[i*4+3] = __float2bfloat16(v.w);
  }
}

// ---------------------------------------------------------------------------
// WT[n][k] (bf16) = W[k][n] (dtype per flag). Tiled 32x32 transpose.
// ---------------------------------------------------------------------------
__global__ __launch_bounds__(256) void wt_cvt(
    const void* __restrict__ W, bf16* __restrict__ WT,
    const int K, const int Nd, const int* __restrict__ flag)
{
  __shared__ float t[32][33];
  const int fl = *flag;
  const int n0 = blockIdx.x * 32, k0 = blockIdx.y * 32;
  const int tx = threadIdx.x & 31, ty = threadIdx.x >> 5;   // 32 x 8
  for (int kk = ty; kk < 32; kk += 8) {
    const size_t gi = (size_t)(k0 + kk) * Nd + (n0 + tx);
    t[kk][tx] = fl ? tof(((const bf16*)W)[gi]) : ((const float*)W)[gi];
  }
  __syncthreads();
  for (int nn = ty; nn < 32; nn += 8)
    WT[(size_t)(n0 + nn) * K + (k0 + tx)] = __float2bfloat16(t[tx][nn]);
}

// ---------------------------------------------------------------------------
// Fused qkv GEMM + bias + RoPE + layout scatter.
// Outputs: Qp[bh][n][64] (rope'd, x0.125), Kp[bh][n][64] (rope'd),
//          Vt[bh][64][n] (transposed via LDS -> coalesced 128B stores).
// t = colbase/768 is BLOCK-uniform (768 = 6 x 128-col tiles per tensor).
// ALL outputs (Q/K/V) now go through per-wave LDS re-tile so every global
// store is a 16B uint4 filling contiguous 128B runs (no partial-sector
// writes -> no HBM write amplification / RMW fetches).
// ---------------------------------------------------------------------------
__global__ __launch_bounds__(256) void gemm_qkv_rope(
    const bf16* __restrict__ Ab, const bf16* __restrict__ WT,
    const void* __restrict__ bias, bf16* __restrict__ Qp,
    bf16* __restrict__ Kp, bf16* __restrict__ Vtb,
    const int* __restrict__ flag,
    const int* __restrict__ pos_h, const int* __restrict__ pos_w)
{
  const int K = C_;
  const bool bbf = (*flag != 0);

  // 36 KB raw: [0,16K) As, [16K,32K) Bs during K-loop;
  // reused as 4 x 9216 B per-wave re-tile scratch in the epilogue.
  __shared__ __align__(16) char smem[36864];
  unsigned short* As = (unsigned short*)smem;
  unsigned short* Bs = (unsigned short*)(smem + 16384);

  const int tid = threadIdx.x;
  const int l   = tid & 63;
  const int w   = tid >> 6;
  const int wm  = (w & 1) * 64;
  const int wn  = (w >> 1) * 64;
  const int row0 = blockIdx.x * 128;
  const int col0 = blockIdx.y * 128;

  const int trow  = tid >> 3;
  const int tch   = tid & 7;
  const int slotj = tch ^ (trow & 7);
  const bf16* Aptr = Ab + (size_t)(row0 + trow) * K + tch * 8;
  const bf16* Bptr = WT + (size_t)(col0 + trow) * K + tch * 8;
  const int lA = trow * 64 + slotj * 8;

  f32x4 acc[4][4] = {};

  for (int k0 = 0; k0 < K; k0 += 64) {
    uint4 av[4], bv[4];
    #pragma unroll
    for (int i = 0; i < 4; i++) {
      av[i] = *(const uint4*)(Aptr + (size_t)i*32*K + k0);
      bv[i] = *(const uint4*)(Bptr + (size_t)i*32*K + k0);
    }
    __syncthreads();
    #pragma unroll
    for (int i = 0; i < 4; i++) {
      *(uint4*)&As[lA + i*2048] = av[i];
      *(uint4*)&Bs[lA + i*2048] = bv[i];
    }
    __syncthreads();
    #pragma unroll
    for (int s = 0; s < 2; s++) {
      bf16x8 af[4], bg[4];
      const int ch = (s*4 + (l >> 4)) ^ (l & 7);
      #pragma unroll
      for (int i = 0; i < 4; i++) {
        const int rowm = wm + i*16 + (l & 15);
        const int rown = wn + i*16 + (l & 15);
        af[i] = *(const bf16x8*)&As[rowm*64 + ch*8];
        bg[i] = *(const bf16x8*)&Bs[rown*64 + ch*8];
      }
      #pragma unroll
      for (int i = 0; i < 4; i++)
        #pragma unroll
        for (int j = 0; j < 4; j++)
          acc[i][j] = __builtin_amdgcn_mfma_f32_16x16x32_bf16(
                          af[i], bg[j], acc[i][j], 0, 0, 0);
    }
  }

  // ---- fused epilogue ----
  const int colbase = col0 + wn;            // multiple of 64
  const int t   = colbase / 768;            // 0=q 1=k 2=v (block-uniform)
  const int h   = (colbase % 768) >> 6;     // head (wave-uniform)
  const int dd0 = l & 15;
  float bv4[4];
  #pragma unroll
  for (int j = 0; j < 4; j++) {
    const int c = colbase + dd0 + j*16;
    bv4[j] = bbf ? tof(((const bf16*)bias)[c]) : ((const float*)bias)[c];
  }
  const int rb = row0 + wm + (l >> 4) * 4;

  __syncthreads();                           // As/Bs dead for ALL waves
  bf16* Ts = (bf16*)(smem + w * 9216);       // 64 rows x 72 elems (144 B)

  if (t == 2) {
    // ---- V: write transposed (d-major) into Ts ----
    #pragma unroll
    for (int i = 0; i < 4; i++) {
      #pragma unroll
      for (int v = 0; v < 4; v++) {
        const int nl = i*16 + ((l >> 4) << 2) + v;   // n_local 0..63
        #pragma unroll
        for (int j = 0; j < 4; j++) {
          const int dl = dd0 + j*16;                 // d_local 0..63
          const float y = acc[i][j][v] + bv4[j];
          Ts[dl*72 + (((nl >> 3) ^ (dl & 7)) << 3) + (nl & 7)] =
              __float2bfloat16(y);
        }
      }
    }
  } else {
    // ---- Q/K: RoPE in-register, write row-major (n-major) into Ts ----
    const int fi  = dd0 >> 1;
    const float LOG2B = 13.287712379549449f;  // log2(10000)
    const float f1 = exp2f(-LOG2B * (float)fi       * (1.0f/16.0f));
    const float f2 = exp2f(-LOG2B * (float)(fi + 8) * (1.0f/16.0f));
    #pragma unroll
    for (int i = 0; i < 4; i++) {
      #pragma unroll
      for (int v = 0; v < 4; v++) {
        const int r  = rb + i*16 + v;          // chunk-local row (global)
        const int rl = i*16 + (l >> 4)*4 + v;  // row local to wave 0..63
        float y0 = acc[i][0][v] + bv4[0];
        float y1 = acc[i][1][v] + bv4[1];
        float y2 = acc[i][2][v] + bv4[2];
        float y3 = acc[i][3][v] + bv4[3];
        const float ph = (float)pos_h[r];
        const float pw = (float)pos_w[r];
        float s1,c1,s2,c2,s3,c3,s4,c4;
        __sincosf(ph*f1, &s1, &c1);
        __sincosf(ph*f2, &s2, &c2);
        __sincosf(pw*f1, &s3, &c3);
        __sincosf(pw*f2, &s4, &c4);
        float z[4];
        z[0] = y0*c1 - y1*s1;
        z[1] = y1*c2 + y0*s2;
        z[2] = y2*c3 - y3*s3;
        z[3] = y3*c4 + y2*s4;
        if (t == 0) { z[0]*=0.125f; z[1]*=0.125f; z[2]*=0.125f; z[3]*=0.125f; }
        #pragma unroll
        for (int j = 0; j < 4; j++) {
          const int cl = dd0 + j*16;           // col local 0..63
          Ts[rl*72 + (((cl >> 3) ^ (rl & 7)) << 3) + (cl & 7)] =
              __float2bfloat16(z[j]);
        }
      }
    }
  }
  __syncthreads();                           // ds_writes visible (in-block)

  if (t == 2) {
    // ---- coalesced V^T stores: 8 lanes fill a contiguous 128B run ----
    const int n0 = (row0 + wm) & 1023;
    const int bp = (row0 + wm) >> 10;
    const size_t gbase = (size_t)(bp*12 + h) * 65536;   // [bh][64][1024]
    #pragma unroll
    for (int dr = 0; dr < 8; dr++) {
      const int dl = dr*8 + (l >> 3);
      const int c  = l & 7;                  // logical 8-elem chunk
      uint4 vv = *(const uint4*)&Ts[dl*72 + ((c ^ (dl & 7)) << 3)];
      *(uint4*)&Vtb[gbase + (size_t)dl*1024 + n0 + c*8] = vv;
    }
  } else {
    // ---- coalesced Q/K stores: full 128B rows of [bh][n][64] ----
    bf16* dst = (t == 0) ? Qp : Kp;
    const int rg0 = row0 + wm;               // 64-row block, one bp
    const int bp  = rg0 >> 10;
    const int nb  = rg0 & 1023;
    const size_t gbase = (size_t)(bp*12 + h) * 65536;   // [bh][1024][64]
    #pragma unroll
    for (int dr = 0; dr < 8; dr++) {
      const int rl = dr*8 + (l >> 3);
      const int c  = l & 7;
      uint4 vv = *(const uint4*)&Ts[rl*72 + ((c ^ (rl & 7)) << 3)];
      *(uint4*)&dst[gbase + (size_t)(nb + rl)*64 + c*8] = vv;
    }
  }
}

// ---------------------------------------------------------------------------
// MFMA flash attention. Block = (q-tile of 64, bh). 4 waves; wave owns 16
// q-rows. All LDS tiles XOR-swizzled; fragment reads at bank floor.
// Epilogue re-tiles through Ps (wave-private region) for 16B coalesced
// ao stores.
// ---------------------------------------------------------------------------
__global__ __launch_bounds__(256) void attn_mfma(
    const bf16* __restrict__ Qp, const bf16* __restrict__ Kp,
    const bf16* __restrict__ Vtb, bf16* __restrict__ ao)
{
  __shared__ __align__(16) bf16 Qs[64*64];
  __shared__ __align__(16) bf16 Ks[64*64];
  __shared__ __align__(16) bf16 Vs[64*64];   // V^T tile: rows=d, cols=kk
  __shared__ __align__(16) bf16 Ps[64*64];   // P, per-wave 16-row regions
  const int tid = threadIdx.x;
  const int l   = tid & 63;
  const int w   = tid >> 6;
  const int qt  = blockIdx.x;                // 0..15
  const int bh  = blockIdx.y;                // chunk-local b*12 + h
  const size_t base = (size_t)bh * 65536;

  #pragma unroll
  for (int i = 0; i < 2; i++) {
    const int idx = tid + i*256;
    const int row = idx >> 3, ch = idx & 7;
    const int slot = ch ^ (row & 7);
    *(uint4*)&Qs[row*64 + slot*8] =
        *(const uint4*)(Qp + base + (size_t)(qt*64 + row)*64 + ch*8);
  }
  __syncthreads();

  bf16x8 af[2];
  {
    const int row = w*16 + (l & 15);
    #pragma unroll
    for (int s = 0; s < 2; s++) {
      const int ch = (s*4 + (l >> 4)) ^ (row & 7);
      af[s] = *(const bf16x8*)&Qs[row*64 + ch*8];
    }
  }

  float m_i[4], l_i[4];
  #pragma unroll
  for (int v = 0; v < 4; v++) { m_i[v] = -3.0e38f; l_i[v] = 0.f; }
  f32x4 o[4] = {};

  for (int kt = 0; kt < 16; kt++) {
    __syncthreads();
    #pragma unroll
    for (int i = 0; i < 2; i++) {
      const int idx = tid + i*256;
      const int row = idx >> 3, ch = idx & 7;
      const int slot = ch ^ (row & 7);
      *(uint4*)&Ks[row*64 + slot*8] =
          *(const uint4*)(Kp + base + (size_t)(kt*64 + row)*64 + ch*8);
      *(uint4*)&Vs[row*64 + slot*8] =
          *(const uint4*)(Vtb + base + (size_t)row*1024 + kt*64 + ch*8);
    }
    __syncthreads();

    f32x4 s[4];
    #pragma unroll
    for (int nt = 0; nt < 4; nt++) {
      f32x4 a = {};
      const int nrow = nt*16 + (l & 15);
      #pragma unroll
      for (int ss = 0; ss < 2; ss++) {
        const int ch = (ss*4 + (l >> 4)) ^ (nrow & 7);
        bf16x8 bg = *(const bf16x8*)&Ks[nrow*64 + ch*8];
        a = __builtin_amdgcn_mfma_f32_16x16x32_bf16(af[ss], bg, a, 0, 0, 0);
      }
      s[nt] = a;
    }

    #pragma unroll
    for (int v = 0; v < 4; v++) {
      float m0 = fmaxf(fmaxf(s[0][v], s[1][v]), fmaxf(s[2][v], s[3][v]));
      #pragma unroll
      for (int off = 1; off < 16; off <<= 1)
        m0 = fmaxf(m0, __shfl_xor(m0, off));
      const float mx = fmaxf(m_i[v], m0);
      const float alpha = exp2f((m_i[v] - mx) * 1.4426950408889634f);
      m_i[v] = mx;
      float r = 0.f;
      #pragma unroll
      for (int nt = 0; nt < 4; nt++) {
        const float p = exp2f((s[nt][v] - mx) * 1.4426950408889634f);
        s[nt][v] = p;
        r += p;
      }
      #pragma unroll
      for (int off = 1; off < 16; off <<= 1)
        r += __shfl_xor(r, off);
      l_i[v] = l_i[v] * alpha + r;
      #pragma unroll
      for (int nt = 0; nt < 4; nt++) o[nt][v] *= alpha;
    }

    #pragma unroll
    for (int nt = 0; nt < 4; nt++) {
      const int kk = nt*16 + (l & 15);
      #pragma unroll
      for (int v = 0; v < 4; v++) {
        const int row = w*16 + (l >> 4)*4 + v;
        const int ch  = (kk >> 3) ^ (row & 7);
        Ps[row*64 + ch*8 + (kk & 7)] = __float2bfloat16(s[nt][v]);
      }
    }

    #pragma unroll
    for (int ss = 0; ss < 2; ss++) {
      const int prow = w*16 + (l & 15);
      const int pch  = (ss*4 + (l >> 4)) ^ (prow & 7);
      bf16x8 pa = *(const bf16x8*)&Ps[prow*64 + pch*8];
      #pragma unroll
      for (int ntd = 0; ntd < 4; ntd++) {
        const int drow = ntd*16 + (l & 15);
        const int vch  = (ss*4 + (l >> 4)) ^ (drow & 7);
        bf16x8 vb = *(const bf16x8*)&Vs[drow*64 + vch*8];
        o[ntd] = __builtin_amdgcn_mfma_f32_16x16x32_bf16(pa, vb, o[ntd], 0,0,0);
      }
    }
  }

  // ---- epilogue: re-tile o through Ps (wave-private 16 rows), then
  //      16B coalesced stores (8 lanes fill a contiguous 128B run) ----
  const int b = bh / 12, h = bh - b*12;
  #pragma unroll
  for (int v = 0; v < 4; v++) {
    const float inv = 1.0f / l_i[v];
    const int rl = (l >> 4)*4 + v;             // 0..15 local row
    #pragma unroll
    for (int ntd = 0; ntd < 4; ntd++) {
      const int cl = ntd*16 + (l & 15);        // 0..63 local col
      Ps[(w*16 + rl)*64 + (((cl >> 3) ^ (rl & 7)) << 3) + (cl & 7)] =
          __float2bfloat16(o[ntd][v] * inv);
    }
  }
  // intra-wave write->read on Ps: compiler inserts the lgkmcnt wait
  #pragma unroll
  for (int e = 0; e < 2; e++) {
    const int rl = e*8 + (l >> 3);
    const int c  = l & 7;
    uint4 vv = *(const uint4*)&Ps[(w*16 + rl)*64 + ((c ^ (rl & 7)) << 3)];
    const int r = qt*64 + w*16 + rl;
    *(uint4*)&ao[((size_t)(b*1024 + r)) * 768 + h*64 + c*8] = vv;
  }
}

// ---------------------------------------------------------------------------
// Plain MFMA NT-GEMM + bias (proj). Unchanged (verified).
// ---------------------------------------------------------------------------
__global__ __launch_bounds__(256) void gemm_mfma(
    const bf16* __restrict__ Ab, const bf16* __restrict__ WT,
    const void* __restrict__ bias, void* __restrict__ Cout,
    const int Nd, const int K, const int c_row_off,
    const int* __restrict__ flag, const int bias_mode, const int c_mode)
{
  const int fl = *flag;
  const bool bbf = (bias_mode == 2) ? (fl != 0) : (bias_mode != 0);
  const bool cbf = (c_mode == 2) ? (fl != 0) : (c_mode != 0);

  __shared__ __align__(16) unsigned short As[128*64];
  __shared__ __align__(16) unsigned short Bs[128*64];

  const int tid = threadIdx.x;
  const int l   = tid & 63;
  const int w   = tid >> 6;
  const int wm  = (w & 1) * 64;
  const int wn  = (w >> 1) * 64;
  const int row0 = blockIdx.x * 128;
  const int col0 = blockIdx.y * 128;

  const int trow  = tid >> 3;
  const int tch   = tid & 7;
  const int slotj = tch ^ (trow & 7);
  const bf16* Aptr = Ab + (size_t)(row0 + trow) * K + tch * 8;
  const bf16* Bptr = WT + (size_t)(col0 + trow) * K + tch * 8;
  const int lA = trow * 64 + slotj * 8;

  f32x4 acc[4][4] = {};

  for (int k0 = 0; k0 < K; k0 += 64) {
    uint4 av[4], bv[4];
    #pragma unroll
    for (int i = 0; i < 4; i++) {
      av[i] = *(const uint4*)(Aptr + (size_t)i*32*K + k0);
      bv[i] = *(const uint4*)(Bptr + (size_t)i*32*K + k0);
    }
    __syncthreads();
    #pragma unroll
    for (int i = 0; i < 4; i++) {
      *(uint4*)&As[lA + i*2048] = av[i];
      *(uint4*)&Bs[lA + i*2048] = bv[i];
    }
    __syncthreads();
    #pragma unroll
    for (int s = 0; s < 2; s++) {
      bf16x8 af[4], bg[4];
      const int ch = (s*4 + (l >> 4)) ^ (l & 7);
      #pragma unroll
      for (int i = 0; i < 4; i++) {
        const int rowm = wm + i*16 + (l & 15);
        const int rown = wn + i*16 + (l & 15);
        af[i] = *(const bf16x8*)&As[rowm*64 + ch*8];
        bg[i] = *(const bf16x8*)&Bs[rown*64 + ch*8];
      }
      #pragma unroll
      for (int i = 0; i < 4; i++)
        #pragma unroll
        for (int j = 0; j < 4; j++)
          acc[i][j] = __builtin_amdgcn_mfma_f32_16x16x32_bf16(
                          af[i], bg[j], acc[i][j], 0, 0, 0);
    }
  }

  const int cn    = col0 + wn + (l & 15);
  const int rbase = c_row_off + row0 + wm + (l >> 4) * 4;
  #pragma unroll
  for (int j = 0; j < 4; j++) {
    const int col = cn + j*16;
    const float bval = bbf ? tof(((const bf16*)bias)[col])
                           : ((const float*)bias)[col];
    #pragma unroll
    for (int i = 0; i < 4; i++) {
      #pragma unroll
      for (int v = 0; v < 4; v++) {
        const size_t r = (size_t)(rbase + i*16 + v);
        const float val = acc[i][j][v] + bval;
        if (cbf) ((bf16*)Cout)[r * Nd + col] = __float2bfloat16(val);
        else     ((float*)Cout)[r * Nd + col] = val;
      }
    }
  }
}

// ---------------------------------------------------------------------------
// ws: flag(256B) | WqkvT 3.54MB | WprojT 1.18MB |
//     xb | Qp | Kp | Vt | ao  (each CB*1.57MB)
// ---------------------------------------------------------------------------
extern "C" void kernel_launch(void* const* d_in, const int* in_sizes, int n_in,
                              void* d_out, int out_size, void* d_ws, size_t ws_size,
                              hipStream_t stream)
{
  (void)in_sizes; (void)n_in; (void)out_size;
  const void* x     = d_in[0];
  const void* Wqkv  = d_in[1];
  const void* bqkv  = d_in[2];
  const void* Wproj = d_in[3];
  const void* bproj = d_in[4];
  const int*  pos_h = (const int*)d_in[5];
  const int*  pos_w = (const int*)d_in[6];

  int* flag = (int*)d_ws;
  char* p = (char*)d_ws + 256;
  bf16* WqkvT  = (bf16*)p; p += (size_t)QC_ * C_ * 2;
  bf16* WprojT = (bf16*)p; p += (size_t)C_ * C_ * 2;

  const size_t fixed = 256 + (size_t)QC_*C_*2 + (size_t)C_*C_*2;
  const size_t perb  = 5 * (size_t)N_ * C_ * 2;   // xb,Qp,Kp,Vt,ao
  int CB = 4;
  if (ws_size < fixed + 4*perb) CB = 2;
  if (ws_size < fixed + 2*perb) CB = 1;
  const int Mc = CB * N_;
  const size_t tsz = (size_t)Mc * C_;

  bf16* xb  = (bf16*)p;
  bf16* Qp  = xb  + tsz;
  bf16* Kp  = Qp  + tsz;
  bf16* Vtb = Kp  + tsz;
  bf16* ao  = Vtb + tsz;

  detect_dtype<<<1, 256, 0, stream>>>((const unsigned*)x, flag);
  wt_cvt<<<dim3(QC_/32, C_/32), 256, 0, stream>>>(Wqkv, WqkvT, C_, QC_, flag);
  wt_cvt<<<dim3(C_/32,  C_/32), 256, 0, stream>>>(Wproj, WprojT, C_, C_, flag);

  for (int c0 = 0; c0 < B_; c0 += CB) {
    const int n4 = Mc * C_ / 4;
    cvt_x<<<(n4 + 255)/256, 256, 0, stream>>>(x, xb, flag, n4, c0 * N_ * C_ / 4);
    gemm_qkv_rope<<<dim3(Mc/128, QC_/128), 256, 0, stream>>>(
        xb, WqkvT, bqkv, Qp, Kp, Vtb, flag,
        pos_h + (size_t)c0*N_, pos_w + (size_t)c0*N_);
    attn_mfma<<<dim3(N_/64, CB*H_), 256, 0, stream>>>(Qp, Kp, Vtb, ao);
    gemm_mfma<<<dim3(Mc/128, C_/128), 256, 0, stream>>>(
        ao, WprojT, bproj, d_out, C_, C_, c0*N_, flag, 2, 2);
  }
}

// Round 2
// 736.327 us; speedup vs baseline: 1.1637x; 1.1594x over previous
//
#include <hip/hip_runtime.h>
#include <hip/hip_bf16.h>

#define B_ 16
#define N_ 1024
#define C_ 768
#define H_ 12
#define HD_ 64
#define QC_ (3*C_)      // 2304

using bf16 = __hip_bfloat16;
using bf16x8 = __attribute__((ext_vector_type(8))) __bf16;
using f32x4  = __attribute__((ext_vector_type(4))) float;

__device__ __forceinline__ float tof(bf16 v){ return __bfloat162float(v); }

// XCD-aware bijective block swizzle: physical bid -> logical lb such that
// each XCD (bid%8) owns a CONTIGUOUS chunk of logical tile space.
// Requires nwg % 8 == 0 (all our grids satisfy this).
__device__ __forceinline__ int xcd_swizzle(int bid, int nwg) {
  return (bid & 7) * (nwg >> 3) + (bid >> 3);
}

// ---------------------------------------------------------------------------
// Input-dtype detector (1=bf16, 0=fp32) from bits 14:7 of sampled words.
// ---------------------------------------------------------------------------
__global__ __launch_bounds__(256) void detect_dtype(
    const unsigned* __restrict__ x32, int* __restrict__ flag)
{
  __shared__ int cnt;
  if (threadIdx.x == 0) cnt = 0;
  __syncthreads();
  int local = 0;
  #pragma unroll
  for (int i = 0; i < 16; i++) {
    unsigned u = x32[threadIdx.x * 16 + i * 4096];
    unsigned e = (u >> 7) & 0xFF;
    local += (e >= 110 && e <= 140) ? 1 : 0;
  }
  atomicAdd(&cnt, local);
  __syncthreads();
  if (threadIdx.x == 0) *flag = (cnt > 2048) ? 1 : 0;
}

// ---------------------------------------------------------------------------
// Cast x (fp32 or bf16 per flag) -> bf16, 4 elems/thread.
// ---------------------------------------------------------------------------
__global__ __launch_bounds__(256) void cvt_x(
    const void* __restrict__ x, bf16* __restrict__ xb,
    const int* __restrict__ flag, const int n4, const int off4)
{
  const int i = blockIdx.x * 256 + threadIdx.x;
  if (i >= n4) return;
  if (*flag) {
    ((uint2*)xb)[i] = ((const uint2*)x)[off4 + i];
  } else {
    float4 v = ((const float4*)x)[off4 + i];
    xb[i*4+0] = __float2bfloat16(v.x);
    xb[i*4+1] = __float2bfloat16(v.y);
    xb[i*4+2] = __float2bfloat16(v.z);
    xb[i*4+3] = __float2bfloat16(v.w);
  }
}

// ---------------------------------------------------------------------------
// WT[n][k] (bf16) = W[k][n] (dtype per flag). Tiled 32x32 transpose.
// ---------------------------------------------------------------------------
__global__ __launch_bounds__(256) void wt_cvt(
    const void* __restrict__ W, bf16* __restrict__ WT,
    const int K, const int Nd, const int* __restrict__ flag)
{
  __shared__ float t[32][33];
  const int fl = *flag;
  const int n0 = blockIdx.x * 32, k0 = blockIdx.y * 32;
  const int tx = threadIdx.x & 31, ty = threadIdx.x >> 5;   // 32 x 8
  for (int kk = ty; kk < 32; kk += 8) {
    const size_t gi = (size_t)(k0 + kk) * Nd + (n0 + tx);
    t[kk][tx] = fl ? tof(((const bf16*)W)[gi]) : ((const float*)W)[gi];
  }
  __syncthreads();
  for (int nn = ty; nn < 32; nn += 8)
    WT[(size_t)(n0 + nn) * K + (k0 + tx)] = __float2bfloat16(t[tx][nn]);
}

// ---------------------------------------------------------------------------
// Fused qkv GEMM + bias + RoPE + layout scatter.
// Changes this round:
//  * XCD swizzle: logical tiles row-slab-major -> each XCD works on 4 A-rows
//    x all 18 cols (A 0.8MB + B 3.5MB ~ L2-resident).
//  * Register-prefetch pipeline: next K-tile's global loads issue right
//    after ds_write of current, hiding L2/L3 latency under MFMA.
// ---------------------------------------------------------------------------
__global__ __launch_bounds__(256) void gemm_qkv_rope(
    const bf16* __restrict__ Ab, const bf16* __restrict__ WT,
    const void* __restrict__ bias, bf16* __restrict__ Qp,
    bf16* __restrict__ Kp, bf16* __restrict__ Vtb,
    const int* __restrict__ flag,
    const int* __restrict__ pos_h, const int* __restrict__ pos_w)
{
  const int K = C_;
  const bool bbf = (*flag != 0);

  __shared__ __align__(16) char smem[36864];
  unsigned short* As = (unsigned short*)smem;
  unsigned short* Bs = (unsigned short*)(smem + 16384);

  const int tid = threadIdx.x;
  const int l   = tid & 63;
  const int w   = tid >> 6;
  const int wm  = (w & 1) * 64;
  const int wn  = (w >> 1) * 64;

  // XCD-aware swizzle; logical index row-major over (rows, cols=gridDim.y)
  const int nwg = gridDim.x * gridDim.y;
  const int bid = blockIdx.y * gridDim.x + blockIdx.x;
  const int lb  = xcd_swizzle(bid, nwg);
  const int gy  = gridDim.y;                 // 18
  const int brow = lb / gy;
  const int bcol = lb - brow * gy;
  const int row0 = brow * 128;
  const int col0 = bcol * 128;

  const int trow  = tid >> 3;
  const int tch   = tid & 7;
  const int slotj = tch ^ (trow & 7);
  const bf16* Aptr = Ab + (size_t)(row0 + trow) * K + tch * 8;
  const bf16* Bptr = WT + (size_t)(col0 + trow) * K + tch * 8;
  const int lA = trow * 64 + slotj * 8;

  f32x4 acc[4][4] = {};

  uint4 av[4], bv[4];
  #pragma unroll
  for (int i = 0; i < 4; i++) {              // prologue: stage k0=0
    av[i] = *(const uint4*)(Aptr + (size_t)i*32*K);
    bv[i] = *(const uint4*)(Bptr + (size_t)i*32*K);
  }

  for (int k0 = 0; k0 < K; k0 += 64) {
    __syncthreads();                         // prev iter's LDS reads done
    #pragma unroll
    for (int i = 0; i < 4; i++) {
      *(uint4*)&As[lA + i*2048] = av[i];
      *(uint4*)&Bs[lA + i*2048] = bv[i];
    }
    if (k0 + 64 < K) {                       // issue NEXT tile loads now
      #pragma unroll
      for (int i = 0; i < 4; i++) {
        av[i] = *(const uint4*)(Aptr + (size_t)i*32*K + k0 + 64);
        bv[i] = *(const uint4*)(Bptr + (size_t)i*32*K + k0 + 64);
      }
    }
    __syncthreads();                         // LDS writes visible
    #pragma unroll
    for (int s = 0; s < 2; s++) {
      bf16x8 af[4], bg[4];
      const int ch = (s*4 + (l >> 4)) ^ (l & 7);
      #pragma unroll
      for (int i = 0; i < 4; i++) {
        const int rowm = wm + i*16 + (l & 15);
        const int rown = wn + i*16 + (l & 15);
        af[i] = *(const bf16x8*)&As[rowm*64 + ch*8];
        bg[i] = *(const bf16x8*)&Bs[rown*64 + ch*8];
      }
      #pragma unroll
      for (int i = 0; i < 4; i++)
        #pragma unroll
        for (int j = 0; j < 4; j++)
          acc[i][j] = __builtin_amdgcn_mfma_f32_16x16x32_bf16(
                          af[i], bg[j], acc[i][j], 0, 0, 0);
    }
  }

  // ---- fused epilogue ----
  const int colbase = col0 + wn;            // multiple of 64
  const int t   = colbase / 768;            // 0=q 1=k 2=v (block-uniform)
  const int h   = (colbase % 768) >> 6;     // head (wave-uniform)
  const int dd0 = l & 15;
  float bv4[4];
  #pragma unroll
  for (int j = 0; j < 4; j++) {
    const int c = colbase + dd0 + j*16;
    bv4[j] = bbf ? tof(((const bf16*)bias)[c]) : ((const float*)bias)[c];
  }
  const int rb = row0 + wm + (l >> 4) * 4;

  __syncthreads();                           // As/Bs dead for ALL waves
  bf16* Ts = (bf16*)(smem + w * 9216);       // 64 rows x 72 elems (144 B)

  if (t == 2) {
    // ---- V: write transposed (d-major) into Ts ----
    #pragma unroll
    for (int i = 0; i < 4; i++) {
      #pragma unroll
      for (int v = 0; v < 4; v++) {
        const int nl = i*16 + ((l >> 4) << 2) + v;   // n_local 0..63
        #pragma unroll
        for (int j = 0; j < 4; j++) {
          const int dl = dd0 + j*16;                 // d_local 0..63
          const float y = acc[i][j][v] + bv4[j];
          Ts[dl*72 + (((nl >> 3) ^ (dl & 7)) << 3) + (nl & 7)] =
              __float2bfloat16(y);
        }
      }
    }
  } else {
    // ---- Q/K: RoPE in-register, write row-major (n-major) into Ts ----
    const int fi  = dd0 >> 1;
    const float LOG2B = 13.287712379549449f;  // log2(10000)
    const float f1 = exp2f(-LOG2B * (float)fi       * (1.0f/16.0f));
    const float f2 = exp2f(-LOG2B * (float)(fi + 8) * (1.0f/16.0f));
    #pragma unroll
    for (int i = 0; i < 4; i++) {
      #pragma unroll
      for (int v = 0; v < 4; v++) {
        const int r  = rb + i*16 + v;          // chunk-local row (global)
        const int rl = i*16 + (l >> 4)*4 + v;  // row local to wave 0..63
        float y0 = acc[i][0][v] + bv4[0];
        float y1 = acc[i][1][v] + bv4[1];
        float y2 = acc[i][2][v] + bv4[2];
        float y3 = acc[i][3][v] + bv4[3];
        const float ph = (float)pos_h[r];
        const float pw = (float)pos_w[r];
        float s1,c1,s2,c2,s3,c3,s4,c4;
        __sincosf(ph*f1, &s1, &c1);
        __sincosf(ph*f2, &s2, &c2);
        __sincosf(pw*f1, &s3, &c3);
        __sincosf(pw*f2, &s4, &c4);
        float z[4];
        z[0] = y0*c1 - y1*s1;
        z[1] = y1*c2 + y0*s2;
        z[2] = y2*c3 - y3*s3;
        z[3] = y3*c4 + y2*s4;
        if (t == 0) { z[0]*=0.125f; z[1]*=0.125f; z[2]*=0.125f; z[3]*=0.125f; }
        #pragma unroll
        for (int j = 0; j < 4; j++) {
          const int cl = dd0 + j*16;           // col local 0..63
          Ts[rl*72 + (((cl >> 3) ^ (rl & 7)) << 3) + (cl & 7)] =
              __float2bfloat16(z[j]);
        }
      }
    }
  }
  __syncthreads();                           // ds_writes visible (in-block)

  if (t == 2) {
    // ---- coalesced V^T stores: 8 lanes fill a contiguous 128B run ----
    const int n0 = (row0 + wm) & 1023;
    const int bp = (row0 + wm) >> 10;
    const size_t gbase = (size_t)(bp*12 + h) * 65536;   // [bh][64][1024]
    #pragma unroll
    for (int dr = 0; dr < 8; dr++) {
      const int dl = dr*8 + (l >> 3);
      const int c  = l & 7;                  // logical 8-elem chunk
      uint4 vv = *(const uint4*)&Ts[dl*72 + ((c ^ (dl & 7)) << 3)];
      *(uint4*)&Vtb[gbase + (size_t)dl*1024 + n0 + c*8] = vv;
    }
  } else {
    // ---- coalesced Q/K stores: full 128B rows of [bh][n][64] ----
    bf16* dst = (t == 0) ? Qp : Kp;
    const int rg0 = row0 + wm;               // 64-row block, one bp
    const int bp  = rg0 >> 10;
    const int nb  = rg0 & 1023;
    const size_t gbase = (size_t)(bp*12 + h) * 65536;   // [bh][1024][64]
    #pragma unroll
    for (int dr = 0; dr < 8; dr++) {
      const int rl = dr*8 + (l >> 3);
      const int c  = l & 7;
      uint4 vv = *(const uint4*)&Ts[rl*72 + ((c ^ (rl & 7)) << 3)];
      *(uint4*)&dst[gbase + (size_t)(nb + rl)*64 + c*8] = vv;
    }
  }
}

// ---------------------------------------------------------------------------
// MFMA flash attention. Block = (q-tile of 64, bh). 4 waves; wave owns 16
// q-rows. XCD swizzle: logical order bh-major -> each XCD's chunk covers few
// bh slices (K/V L2-resident). kt-loop register-prefetch pipeline.
// ---------------------------------------------------------------------------
__global__ __launch_bounds__(256) void attn_mfma(
    const bf16* __restrict__ Qp, const bf16* __restrict__ Kp,
    const bf16* __restrict__ Vtb, bf16* __restrict__ ao)
{
  __shared__ __align__(16) bf16 Qs[64*64];
  __shared__ __align__(16) bf16 Ks[64*64];
  __shared__ __align__(16) bf16 Vs[64*64];   // V^T tile: rows=d, cols=kk
  __shared__ __align__(16) bf16 Ps[64*64];   // P, per-wave 16-row regions
  const int tid = threadIdx.x;
  const int l   = tid & 63;
  const int w   = tid >> 6;

  const int nwg = gridDim.x * gridDim.y;
  const int bid = blockIdx.y * gridDim.x + blockIdx.x;
  const int lb  = xcd_swizzle(bid, nwg);     // bh-major logical order
  const int qt  = lb & 15;                   // 0..15
  const int bh  = lb >> 4;                   // chunk-local b*12 + h
  const size_t base = (size_t)bh * 65536;

  const int srow = tid >> 3, sch = tid & 7;  // staging coords (i=0 half)
  const int sslot = sch ^ (srow & 7);

  #pragma unroll
  for (int i = 0; i < 2; i++) {
    const int idx = tid + i*256;
    const int row = idx >> 3, ch = idx & 7;
    const int slot = ch ^ (row & 7);
    *(uint4*)&Qs[row*64 + slot*8] =
        *(const uint4*)(Qp + base + (size_t)(qt*64 + row)*64 + ch*8);
  }
  __syncthreads();

  bf16x8 af[2];
  {
    const int row = w*16 + (l & 15);
    #pragma unroll
    for (int s = 0; s < 2; s++) {
      const int ch = (s*4 + (l >> 4)) ^ (row & 7);
      af[s] = *(const bf16x8*)&Qs[row*64 + ch*8];
    }
  }

  float m_i[4], l_i[4];
  #pragma unroll
  for (int v = 0; v < 4; v++) { m_i[v] = -3.0e38f; l_i[v] = 0.f; }
  f32x4 o[4] = {};

  // prologue: stage kt=0 K/V into registers
  uint4 kpre[2], vpre[2];
  #pragma unroll
  for (int i = 0; i < 2; i++) {
    const int row = srow + i*32;
    kpre[i] = *(const uint4*)(Kp  + base + (size_t)row*64 + sch*8);
    vpre[i] = *(const uint4*)(Vtb + base + (size_t)row*1024 + sch*8);
  }

  for (int kt = 0; kt < 16; kt++) {
    __syncthreads();                         // prev iter's LDS reads done
    #pragma unroll
    for (int i = 0; i < 2; i++) {
      const int row = srow + i*32;
      const int slot = sch ^ (row & 7);
      (void)slot;
      *(uint4*)&Ks[row*64 + (sch ^ (row & 7))*8] = kpre[i];
      *(uint4*)&Vs[row*64 + (sch ^ (row & 7))*8] = vpre[i];
    }
    if (kt < 15) {                           // issue NEXT tile loads
      #pragma unroll
      for (int i = 0; i < 2; i++) {
        const int row = srow + i*32;
        kpre[i] = *(const uint4*)(Kp  + base + (size_t)((kt+1)*64 + row)*64 + sch*8);
        vpre[i] = *(const uint4*)(Vtb + base + (size_t)row*1024 + (kt+1)*64 + sch*8);
      }
    }
    __syncthreads();

    f32x4 s[4];
    #pragma unroll
    for (int nt = 0; nt < 4; nt++) {
      f32x4 a = {};
      const int nrow = nt*16 + (l & 15);
      #pragma unroll
      for (int ss = 0; ss < 2; ss++) {
        const int ch = (ss*4 + (l >> 4)) ^ (nrow & 7);
        bf16x8 bg = *(const bf16x8*)&Ks[nrow*64 + ch*8];
        a = __builtin_amdgcn_mfma_f32_16x16x32_bf16(af[ss], bg, a, 0, 0, 0);
      }
      s[nt] = a;
    }

    #pragma unroll
    for (int v = 0; v < 4; v++) {
      float m0 = fmaxf(fmaxf(s[0][v], s[1][v]), fmaxf(s[2][v], s[3][v]));
      #pragma unroll
      for (int off = 1; off < 16; off <<= 1)
        m0 = fmaxf(m0, __shfl_xor(m0, off));
      const float mx = fmaxf(m_i[v], m0);
      const float alpha = exp2f((m_i[v] - mx) * 1.4426950408889634f);
      m_i[v] = mx;
      float r = 0.f;
      #pragma unroll
      for (int nt = 0; nt < 4; nt++) {
        const float p = exp2f((s[nt][v] - mx) * 1.4426950408889634f);
        s[nt][v] = p;
        r += p;
      }
      #pragma unroll
      for (int off = 1; off < 16; off <<= 1)
        r += __shfl_xor(r, off);
      l_i[v] = l_i[v] * alpha + r;
      #pragma unroll
      for (int nt = 0; nt < 4; nt++) o[nt][v] *= alpha;
    }

    #pragma unroll
    for (int nt = 0; nt < 4; nt++) {
      const int kk = nt*16 + (l & 15);
      #pragma unroll
      for (int v = 0; v < 4; v++) {
        const int row = w*16 + (l >> 4)*4 + v;
        const int ch  = (kk >> 3) ^ (row & 7);
        Ps[row*64 + ch*8 + (kk & 7)] = __float2bfloat16(s[nt][v]);
      }
    }

    #pragma unroll
    for (int ss = 0; ss < 2; ss++) {
      const int prow = w*16 + (l & 15);
      const int pch  = (ss*4 + (l >> 4)) ^ (prow & 7);
      bf16x8 pa = *(const bf16x8*)&Ps[prow*64 + pch*8];
      #pragma unroll
      for (int ntd = 0; ntd < 4; ntd++) {
        const int drow = ntd*16 + (l & 15);
        const int vch  = (ss*4 + (l >> 4)) ^ (drow & 7);
        bf16x8 vb = *(const bf16x8*)&Vs[drow*64 + vch*8];
        o[ntd] = __builtin_amdgcn_mfma_f32_16x16x32_bf16(pa, vb, o[ntd], 0,0,0);
      }
    }
  }

  // ---- epilogue: re-tile o through Ps (wave-private 16 rows), then
  //      16B coalesced stores ----
  const int b = bh / 12, h = bh - b*12;
  #pragma unroll
  for (int v = 0; v < 4; v++) {
    const float inv = 1.0f / l_i[v];
    const int rl = (l >> 4)*4 + v;             // 0..15 local row
    #pragma unroll
    for (int ntd = 0; ntd < 4; ntd++) {
      const int cl = ntd*16 + (l & 15);        // 0..63 local col
      Ps[(w*16 + rl)*64 + (((cl >> 3) ^ (rl & 7)) << 3) + (cl & 7)] =
          __float2bfloat16(o[ntd][v] * inv);
    }
  }
  #pragma unroll
  for (int e = 0; e < 2; e++) {
    const int rl = e*8 + (l >> 3);
    const int c  = l & 7;
    uint4 vv = *(const uint4*)&Ps[(w*16 + rl)*64 + ((c ^ (rl & 7)) << 3)];
    const int r = qt*64 + w*16 + rl;
    *(uint4*)&ao[((size_t)(b*1024 + r)) * 768 + h*64 + c*8] = vv;
  }
}

// ---------------------------------------------------------------------------
// Plain MFMA NT-GEMM + bias (proj). + XCD swizzle + prefetch pipeline.
// ---------------------------------------------------------------------------
__global__ __launch_bounds__(256) void gemm_mfma(
    const bf16* __restrict__ Ab, const bf16* __restrict__ WT,
    const void* __restrict__ bias, void* __restrict__ Cout,
    const int Nd, const int K, const int c_row_off,
    const int* __restrict__ flag, const int bias_mode, const int c_mode)
{
  const int fl = *flag;
  const bool bbf = (bias_mode == 2) ? (fl != 0) : (bias_mode != 0);
  const bool cbf = (c_mode == 2) ? (fl != 0) : (c_mode != 0);

  __shared__ __align__(16) unsigned short As[128*64];
  __shared__ __align__(16) unsigned short Bs[128*64];

  const int tid = threadIdx.x;
  const int l   = tid & 63;
  const int w   = tid >> 6;
  const int wm  = (w & 1) * 64;
  const int wn  = (w >> 1) * 64;

  const int nwg = gridDim.x * gridDim.y;
  const int bid = blockIdx.y * gridDim.x + blockIdx.x;
  const int lb  = xcd_swizzle(bid, nwg);
  const int gy  = gridDim.y;
  const int brow = lb / gy;
  const int bcol = lb - brow * gy;
  const int row0 = brow * 128;
  const int col0 = bcol * 128;

  const int trow  = tid >> 3;
  const int tch   = tid & 7;
  const int slotj = tch ^ (trow & 7);
  const bf16* Aptr = Ab + (size_t)(row0 + trow) * K + tch * 8;
  const bf16* Bptr = WT + (size_t)(col0 + trow) * K + tch * 8;
  const int lA = trow * 64 + slotj * 8;

  f32x4 acc[4][4] = {};

  uint4 av[4], bv[4];
  #pragma unroll
  for (int i = 0; i < 4; i++) {
    av[i] = *(const uint4*)(Aptr + (size_t)i*32*K);
    bv[i] = *(const uint4*)(Bptr + (size_t)i*32*K);
  }

  for (int k0 = 0; k0 < K; k0 += 64) {
    __syncthreads();
    #pragma unroll
    for (int i = 0; i < 4; i++) {
      *(uint4*)&As[lA + i*2048] = av[i];
      *(uint4*)&Bs[lA + i*2048] = bv[i];
    }
    if (k0 + 64 < K) {
      #pragma unroll
      for (int i = 0; i < 4; i++) {
        av[i] = *(const uint4*)(Aptr + (size_t)i*32*K + k0 + 64);
        bv[i] = *(const uint4*)(Bptr + (size_t)i*32*K + k0 + 64);
      }
    }
    __syncthreads();
    #pragma unroll
    for (int s = 0; s < 2; s++) {
      bf16x8 af[4], bg[4];
      const int ch = (s*4 + (l >> 4)) ^ (l & 7);
      #pragma unroll
      for (int i = 0; i < 4; i++) {
        const int rowm = wm + i*16 + (l & 15);
        const int rown = wn + i*16 + (l & 15);
        af[i] = *(const bf16x8*)&As[rowm*64 + ch*8];
        bg[i] = *(const bf16x8*)&Bs[rown*64 + ch*8];
      }
      #pragma unroll
      for (int i = 0; i < 4; i++)
        #pragma unroll
        for (int j = 0; j < 4; j++)
          acc[i][j] = __builtin_amdgcn_mfma_f32_16x16x32_bf16(
                          af[i], bg[j], acc[i][j], 0, 0, 0);
    }
  }

  const int cn    = col0 + wn + (l & 15);
  const int rbase = c_row_off + row0 + wm + (l >> 4) * 4;
  #pragma unroll
  for (int j = 0; j < 4; j++) {
    const int col = cn + j*16;
    const float bval = bbf ? tof(((const bf16*)bias)[col])
                           : ((const float*)bias)[col];
    #pragma unroll
    for (int i = 0; i < 4; i++) {
      #pragma unroll
      for (int v = 0; v < 4; v++) {
        const size_t r = (size_t)(rbase + i*16 + v);
        const float val = acc[i][j][v] + bval;
        if (cbf) ((bf16*)Cout)[r * Nd + col] = __float2bfloat16(val);
        else     ((float*)Cout)[r * Nd + col] = val;
      }
    }
  }
}

// ---------------------------------------------------------------------------
// ws: flag(256B) | WqkvT 3.54MB | WprojT 1.18MB |
//     xb | Qp | Kp | Vt | ao  (each CB*1.57MB)
// ---------------------------------------------------------------------------
extern "C" void kernel_launch(void* const* d_in, const int* in_sizes, int n_in,
                              void* d_out, int out_size, void* d_ws, size_t ws_size,
                              hipStream_t stream)
{
  (void)in_sizes; (void)n_in; (void)out_size;
  const void* x     = d_in[0];
  const void* Wqkv  = d_in[1];
  const void* bqkv  = d_in[2];
  const void* Wproj = d_in[3];
  const void* bproj = d_in[4];
  const int*  pos_h = (const int*)d_in[5];
  const int*  pos_w = (const int*)d_in[6];

  int* flag = (int*)d_ws;
  char* p = (char*)d_ws + 256;
  bf16* WqkvT  = (bf16*)p; p += (size_t)QC_ * C_ * 2;
  bf16* WprojT = (bf16*)p; p += (size_t)C_ * C_ * 2;

  const size_t fixed = 256 + (size_t)QC_*C_*2 + (size_t)C_*C_*2;
  const size_t perb  = 5 * (size_t)N_ * C_ * 2;   // xb,Qp,Kp,Vt,ao per batch
  int CB = 16;
  if (ws_size < fixed + 16*perb) CB = 8;
  if (ws_size < fixed + 8*perb)  CB = 4;
  if (ws_size < fixed + 4*perb)  CB = 2;
  if (ws_size < fixed + 2*perb)  CB = 1;
  const int Mc = CB * N_;
  const size_t tsz = (size_t)Mc * C_;

  bf16* xb  = (bf16*)p;
  bf16* Qp  = xb  + tsz;
  bf16* Kp  = Qp  + tsz;
  bf16* Vtb = Kp  + tsz;
  bf16* ao  = Vtb + tsz;

  detect_dtype<<<1, 256, 0, stream>>>((const unsigned*)x, flag);
  wt_cvt<<<dim3(QC_/32, C_/32), 256, 0, stream>>>(Wqkv, WqkvT, C_, QC_, flag);
  wt_cvt<<<dim3(C_/32,  C_/32), 256, 0, stream>>>(Wproj, WprojT, C_, C_, flag);

  for (int c0 = 0; c0 < B_; c0 += CB) {
    const int n4 = Mc * C_ / 4;
    cvt_x<<<(n4 + 255)/256, 256, 0, stream>>>(x, xb, flag, n4, c0 * N_ * C_ / 4);
    gemm_qkv_rope<<<dim3(Mc/128, QC_/128), 256, 0, stream>>>(
        xb, WqkvT, bqkv, Qp, Kp, Vtb, flag,
        pos_h + (size_t)c0*N_, pos_w + (size_t)c0*N_);
    attn_mfma<<<dim3(N_/64, CB*H_), 256, 0, stream>>>(Qp, Kp, Vtb, ao);
    gemm_mfma<<<dim3(Mc/128, C_/128), 256, 0, stream>>>(
        ao, WprojT, bproj, d_out, C_, C_, c0*N_, flag, 2, 2);
  }
}

// Round 3
// 434.402 us; speedup vs baseline: 1.9725x; 1.6950x over previous
//
#include <hip/hip_runtime.h>
#include <hip/hip_bf16.h>

#define B_ 16
#define N_ 1024
#define C_ 768
#define H_ 12
#define HD_ 64
#define QC_ (3*C_)      // 2304

using bf16 = __hip_bfloat16;
using bf16x8 = __attribute__((ext_vector_type(8))) __bf16;
using f32x4  = __attribute__((ext_vector_type(4))) float;

__device__ __forceinline__ float tof(bf16 v){ return __bfloat162float(v); }

// Async global->LDS 16B DMA. LDS dest is wave-uniform base + lane*16 (linear);
// swizzle is applied on the per-lane GLOBAL address (rule #21: linear dest +
// inverse-swizzled source + swizzled read).
__device__ __forceinline__ void gload16(const void* g, void* l) {
  __builtin_amdgcn_global_load_lds(
      (const __attribute__((address_space(1))) unsigned int*)g,
      (__attribute__((address_space(3))) unsigned int*)l, 16, 0, 0);
}

// XCD-aware bijective block swizzle: physical bid -> logical lb such that
// each XCD (bid%8) owns a CONTIGUOUS chunk of logical tile space.
// Requires nwg % 8 == 0 (all our grids satisfy this).
__device__ __forceinline__ int xcd_swizzle(int bid, int nwg) {
  return (bid & 7) * (nwg >> 3) + (bid >> 3);
}

// ---------------------------------------------------------------------------
// Input-dtype detector (1=bf16, 0=fp32) from bits 14:7 of sampled words.
// ---------------------------------------------------------------------------
__global__ __launch_bounds__(256) void detect_dtype(
    const unsigned* __restrict__ x32, int* __restrict__ flag)
{
  __shared__ int cnt;
  if (threadIdx.x == 0) cnt = 0;
  __syncthreads();
  int local = 0;
  #pragma unroll
  for (int i = 0; i < 16; i++) {
    unsigned u = x32[threadIdx.x * 16 + i * 4096];
    unsigned e = (u >> 7) & 0xFF;
    local += (e >= 110 && e <= 140) ? 1 : 0;
  }
  atomicAdd(&cnt, local);
  __syncthreads();
  if (threadIdx.x == 0) *flag = (cnt > 2048) ? 1 : 0;
}

// ---------------------------------------------------------------------------
// Cast x (fp32 or bf16 per flag) -> bf16, 4 elems/thread.
// ---------------------------------------------------------------------------
__global__ __launch_bounds__(256) void cvt_x(
    const void* __restrict__ x, bf16* __restrict__ xb,
    const int* __restrict__ flag, const int n4, const int off4)
{
  const int i = blockIdx.x * 256 + threadIdx.x;
  if (i >= n4) return;
  if (*flag) {
    ((uint2*)xb)[i] = ((const uint2*)x)[off4 + i];
  } else {
    float4 v = ((const float4*)x)[off4 + i];
    xb[i*4+0] = __float2bfloat16(v.x);
    xb[i*4+1] = __float2bfloat16(v.y);
    xb[i*4+2] = __float2bfloat16(v.z);
    xb[i*4+3] = __float2bfloat16(v.w);
  }
}

// ---------------------------------------------------------------------------
// WT[n][k] (bf16) = W[k][n] (dtype per flag). Tiled 32x32 transpose.
// ---------------------------------------------------------------------------
__global__ __launch_bounds__(256) void wt_cvt(
    const void* __restrict__ W, bf16* __restrict__ WT,
    const int K, const int Nd, const int* __restrict__ flag)
{
  __shared__ float t[32][33];
  const int fl = *flag;
  const int n0 = blockIdx.x * 32, k0 = blockIdx.y * 32;
  const int tx = threadIdx.x & 31, ty = threadIdx.x >> 5;   // 32 x 8
  for (int kk = ty; kk < 32; kk += 8) {
    const size_t gi = (size_t)(k0 + kk) * Nd + (n0 + tx);
    t[kk][tx] = fl ? tof(((const bf16*)W)[gi]) : ((const float*)W)[gi];
  }
  __syncthreads();
  for (int nn = ty; nn < 32; nn += 8)
    WT[(size_t)(n0 + nn) * K + (k0 + tx)] = __float2bfloat16(t[tx][nn]);
}

// ---------------------------------------------------------------------------
// Fused qkv GEMM + bias + RoPE + layout scatter.
// Round-3 change: staging via global_load_lds (async DMA, no VGPR round
// trip, no ds_write). LDS contents bit-identical to the old reg-staged
// swizzled layout; MFMA fragment reads unchanged.
// ---------------------------------------------------------------------------
__global__ __launch_bounds__(256) void gemm_qkv_rope(
    const bf16* __restrict__ Ab, const bf16* __restrict__ WT,
    const void* __restrict__ bias, bf16* __restrict__ Qp,
    bf16* __restrict__ Kp, bf16* __restrict__ Vtb,
    const int* __restrict__ flag,
    const int* __restrict__ pos_h, const int* __restrict__ pos_w)
{
  const int K = C_;
  const bool bbf = (*flag != 0);

  __shared__ __align__(16) char smem[36864];
  unsigned short* As = (unsigned short*)smem;
  unsigned short* Bs = (unsigned short*)(smem + 16384);

  const int tid = threadIdx.x;
  const int l   = tid & 63;
  const int w   = tid >> 6;
  const int wm  = (w & 1) * 64;
  const int wn  = (w >> 1) * 64;

  // XCD-aware swizzle; logical index row-major over (rows, cols=gridDim.y)
  const int nwg = gridDim.x * gridDim.y;
  const int bid = blockIdx.y * gridDim.x + blockIdx.x;
  const int lb  = xcd_swizzle(bid, nwg);
  const int gy  = gridDim.y;                 // 18
  const int brow = lb / gy;
  const int bcol = lb - brow * gy;
  const int row0 = brow * 128;
  const int col0 = bcol * 128;

  // Staging geometry: wave w, instr i covers rows [i*32+w*8, +8).
  // Lane l -> row (l>>3), slot (l&7); global chunk = (l&7)^(l>>3) so that
  // LDS[row][slot] holds chunk slot^(row&7) (the layout the reads expect).
  const int srow = w*8 + (l >> 3);
  const int sch  = (l & 7) ^ (l >> 3);
  const bf16* Ast = Ab + (size_t)(row0 + srow) * K + sch * 8;
  const bf16* Bst = WT + (size_t)(col0 + srow) * K + sch * 8;

  f32x4 acc[4][4] = {};

  for (int k0 = 0; k0 < K; k0 += 64) {
    __syncthreads();                         // prev iter's LDS reads done
    #pragma unroll
    for (int i = 0; i < 4; i++) {
      gload16(Ast + (size_t)i*32*K + k0, As + (i*32 + w*8)*64);
      gload16(Bst + (size_t)i*32*K + k0, Bs + (i*32 + w*8)*64);
    }
    __syncthreads();                         // drains vmcnt -> LDS ready
    #pragma unroll
    for (int s = 0; s < 2; s++) {
      bf16x8 af[4], bg[4];
      const int ch = (s*4 + (l >> 4)) ^ (l & 7);
      #pragma unroll
      for (int i = 0; i < 4; i++) {
        const int rowm = wm + i*16 + (l & 15);
        const int rown = wn + i*16 + (l & 15);
        af[i] = *(const bf16x8*)&As[rowm*64 + ch*8];
        bg[i] = *(const bf16x8*)&Bs[rown*64 + ch*8];
      }
      #pragma unroll
      for (int i = 0; i < 4; i++)
        #pragma unroll
        for (int j = 0; j < 4; j++)
          acc[i][j] = __builtin_amdgcn_mfma_f32_16x16x32_bf16(
                          af[i], bg[j], acc[i][j], 0, 0, 0);
    }
  }

  // ---- fused epilogue ----
  const int colbase = col0 + wn;            // multiple of 64
  const int t   = colbase / 768;            // 0=q 1=k 2=v (block-uniform)
  const int h   = (colbase % 768) >> 6;     // head (wave-uniform)
  const int dd0 = l & 15;
  float bv4[4];
  #pragma unroll
  for (int j = 0; j < 4; j++) {
    const int c = colbase + dd0 + j*16;
    bv4[j] = bbf ? tof(((const bf16*)bias)[c]) : ((const float*)bias)[c];
  }
  const int rb = row0 + wm + (l >> 4) * 4;

  __syncthreads();                           // As/Bs dead for ALL waves
  bf16* Ts = (bf16*)(smem + w * 9216);       // 64 rows x 72 elems (144 B)

  if (t == 2) {
    // ---- V: write transposed (d-major) into Ts ----
    #pragma unroll
    for (int i = 0; i < 4; i++) {
      #pragma unroll
      for (int v = 0; v < 4; v++) {
        const int nl = i*16 + ((l >> 4) << 2) + v;   // n_local 0..63
        #pragma unroll
        for (int j = 0; j < 4; j++) {
          const int dl = dd0 + j*16;                 // d_local 0..63
          const float y = acc[i][j][v] + bv4[j];
          Ts[dl*72 + (((nl >> 3) ^ (dl & 7)) << 3) + (nl & 7)] =
              __float2bfloat16(y);
        }
      }
    }
  } else {
    // ---- Q/K: RoPE in-register, write row-major (n-major) into Ts ----
    const int fi  = dd0 >> 1;
    const float LOG2B = 13.287712379549449f;  // log2(10000)
    const float f1 = exp2f(-LOG2B * (float)fi       * (1.0f/16.0f));
    const float f2 = exp2f(-LOG2B * (float)(fi + 8) * (1.0f/16.0f));
    #pragma unroll
    for (int i = 0; i < 4; i++) {
      #pragma unroll
      for (int v = 0; v < 4; v++) {
        const int r  = rb + i*16 + v;          // chunk-local row (global)
        const int rl = i*16 + (l >> 4)*4 + v;  // row local to wave 0..63
        float y0 = acc[i][0][v] + bv4[0];
        float y1 = acc[i][1][v] + bv4[1];
        float y2 = acc[i][2][v] + bv4[2];
        float y3 = acc[i][3][v] + bv4[3];
        const float ph = (float)pos_h[r];
        const float pw = (float)pos_w[r];
        float s1,c1,s2,c2,s3,c3,s4,c4;
        __sincosf(ph*f1, &s1, &c1);
        __sincosf(ph*f2, &s2, &c2);
        __sincosf(pw*f1, &s3, &c3);
        __sincosf(pw*f2, &s4, &c4);
        float z[4];
        z[0] = y0*c1 - y1*s1;
        z[1] = y1*c2 + y0*s2;
        z[2] = y2*c3 - y3*s3;
        z[3] = y3*c4 + y2*s4;
        if (t == 0) { z[0]*=0.125f; z[1]*=0.125f; z[2]*=0.125f; z[3]*=0.125f; }
        #pragma unroll
        for (int j = 0; j < 4; j++) {
          const int cl = dd0 + j*16;           // col local 0..63
          Ts[rl*72 + (((cl >> 3) ^ (rl & 7)) << 3) + (cl & 7)] =
              __float2bfloat16(z[j]);
        }
      }
    }
  }
  __syncthreads();                           // ds_writes visible (in-block)

  if (t == 2) {
    // ---- coalesced V^T stores: 8 lanes fill a contiguous 128B run ----
    const int n0 = (row0 + wm) & 1023;
    const int bp = (row0 + wm) >> 10;
    const size_t gbase = (size_t)(bp*12 + h) * 65536;   // [bh][64][1024]
    #pragma unroll
    for (int dr = 0; dr < 8; dr++) {
      const int dl = dr*8 + (l >> 3);
      const int c  = l & 7;                  // logical 8-elem chunk
      uint4 vv = *(const uint4*)&Ts[dl*72 + ((c ^ (dl & 7)) << 3)];
      *(uint4*)&Vtb[gbase + (size_t)dl*1024 + n0 + c*8] = vv;
    }
  } else {
    // ---- coalesced Q/K stores: full 128B rows of [bh][n][64] ----
    bf16* dst = (t == 0) ? Qp : Kp;
    const int rg0 = row0 + wm;               // 64-row block, one bp
    const int bp  = rg0 >> 10;
    const int nb  = rg0 & 1023;
    const size_t gbase = (size_t)(bp*12 + h) * 65536;   // [bh][1024][64]
    #pragma unroll
    for (int dr = 0; dr < 8; dr++) {
      const int rl = dr*8 + (l >> 3);
      const int c  = l & 7;
      uint4 vv = *(const uint4*)&Ts[rl*72 + ((c ^ (rl & 7)) << 3)];
      *(uint4*)&dst[gbase + (size_t)(nb + rl)*64 + c*8] = vv;
    }
  }
}

// ---------------------------------------------------------------------------
// MFMA flash attention. Block = (q-tile of 64, bh). 4 waves; wave owns 16
// q-rows. Q/K/V staged via global_load_lds (async DMA). XCD swizzle keeps
// each XCD's concurrent K/V working set L2-resident.
// ---------------------------------------------------------------------------
__global__ __launch_bounds__(256) void attn_mfma(
    const bf16* __restrict__ Qp, const bf16* __restrict__ Kp,
    const bf16* __restrict__ Vtb, bf16* __restrict__ ao)
{
  __shared__ __align__(16) bf16 Qs[64*64];
  __shared__ __align__(16) bf16 Ks[64*64];
  __shared__ __align__(16) bf16 Vs[64*64];   // V^T tile: rows=d, cols=kk
  __shared__ __align__(16) bf16 Ps[64*64];   // P, per-wave 16-row regions
  const int tid = threadIdx.x;
  const int l   = tid & 63;
  const int w   = tid >> 6;

  const int nwg = gridDim.x * gridDim.y;
  const int bid = blockIdx.y * gridDim.x + blockIdx.x;
  const int lb  = xcd_swizzle(bid, nwg);     // bh-major logical order
  const int qt  = lb & 15;                   // 0..15
  const int bh  = lb >> 4;                   // chunk-local b*12 + h
  const size_t base = (size_t)bh * 65536;

  // Staging geometry (same scheme as gemm): wave w, instr i covers rows
  // [i*32+w*8, +8); lane l -> row l>>3, global chunk (l&7)^(l>>3).
  const int srow = w*8 + (l >> 3);
  const int sch  = (l & 7) ^ (l >> 3);
  const bf16* Qst = Qp  + base + (size_t)(qt*64 + srow)*64 + sch*8;
  const bf16* Kst = Kp  + base + (size_t)srow*64   + sch*8;
  const bf16* Vst = Vtb + base + (size_t)srow*1024 + sch*8;

  #pragma unroll
  for (int i = 0; i < 2; i++)
    gload16(Qst + (size_t)i*32*64, Qs + (i*32 + w*8)*64);
  __syncthreads();                           // drains vmcnt

  bf16x8 af[2];
  {
    const int row = w*16 + (l & 15);
    #pragma unroll
    for (int s = 0; s < 2; s++) {
      const int ch = (s*4 + (l >> 4)) ^ (row & 7);
      af[s] = *(const bf16x8*)&Qs[row*64 + ch*8];
    }
  }

  float m_i[4], l_i[4];
  #pragma unroll
  for (int v = 0; v < 4; v++) { m_i[v] = -3.0e38f; l_i[v] = 0.f; }
  f32x4 o[4] = {};

  for (int kt = 0; kt < 16; kt++) {
    __syncthreads();                         // prev iter's LDS reads done
    #pragma unroll
    for (int i = 0; i < 2; i++) {
      gload16(Kst + (size_t)(kt*64 + i*32)*64, Ks + (i*32 + w*8)*64);
      gload16(Vst + (size_t)i*32*1024 + kt*64, Vs + (i*32 + w*8)*64);
    }
    __syncthreads();                         // drains vmcnt -> tiles ready

    f32x4 s[4];
    #pragma unroll
    for (int nt = 0; nt < 4; nt++) {
      f32x4 a = {};
      const int nrow = nt*16 + (l & 15);
      #pragma unroll
      for (int ss = 0; ss < 2; ss++) {
        const int ch = (ss*4 + (l >> 4)) ^ (nrow & 7);
        bf16x8 bg = *(const bf16x8*)&Ks[nrow*64 + ch*8];
        a = __builtin_amdgcn_mfma_f32_16x16x32_bf16(af[ss], bg, a, 0, 0, 0);
      }
      s[nt] = a;
    }

    #pragma unroll
    for (int v = 0; v < 4; v++) {
      float m0 = fmaxf(fmaxf(s[0][v], s[1][v]), fmaxf(s[2][v], s[3][v]));
      #pragma unroll
      for (int off = 1; off < 16; off <<= 1)
        m0 = fmaxf(m0, __shfl_xor(m0, off));
      const float mx = fmaxf(m_i[v], m0);
      const float alpha = exp2f((m_i[v] - mx) * 1.4426950408889634f);
      m_i[v] = mx;
      float r = 0.f;
      #pragma unroll
      for (int nt = 0; nt < 4; nt++) {
        const float p = exp2f((s[nt][v] - mx) * 1.4426950408889634f);
        s[nt][v] = p;
        r += p;
      }
      #pragma unroll
      for (int off = 1; off < 16; off <<= 1)
        r += __shfl_xor(r, off);
      l_i[v] = l_i[v] * alpha + r;
      #pragma unroll
      for (int nt = 0; nt < 4; nt++) o[nt][v] *= alpha;
    }

    #pragma unroll
    for (int nt = 0; nt < 4; nt++) {
      const int kk = nt*16 + (l & 15);
      #pragma unroll
      for (int v = 0; v < 4; v++) {
        const int row = w*16 + (l >> 4)*4 + v;
        const int ch  = (kk >> 3) ^ (row & 7);
        Ps[row*64 + ch*8 + (kk & 7)] = __float2bfloat16(s[nt][v]);
      }
    }

    #pragma unroll
    for (int ss = 0; ss < 2; ss++) {
      const int prow = w*16 + (l & 15);
      const int pch  = (ss*4 + (l >> 4)) ^ (prow & 7);
      bf16x8 pa = *(const bf16x8*)&Ps[prow*64 + pch*8];
      #pragma unroll
      for (int ntd = 0; ntd < 4; ntd++) {
        const int drow = ntd*16 + (l & 15);
        const int vch  = (ss*4 + (l >> 4)) ^ (drow & 7);
        bf16x8 vb = *(const bf16x8*)&Vs[drow*64 + vch*8];
        o[ntd] = __builtin_amdgcn_mfma_f32_16x16x32_bf16(pa, vb, o[ntd], 0,0,0);
      }
    }
  }

  // ---- epilogue: re-tile o through Ps (wave-private 16 rows), then
  //      16B coalesced stores ----
  const int b = bh / 12, h = bh - b*12;
  #pragma unroll
  for (int v = 0; v < 4; v++) {
    const float inv = 1.0f / l_i[v];
    const int rl = (l >> 4)*4 + v;             // 0..15 local row
    #pragma unroll
    for (int ntd = 0; ntd < 4; ntd++) {
      const int cl = ntd*16 + (l & 15);        // 0..63 local col
      Ps[(w*16 + rl)*64 + (((cl >> 3) ^ (rl & 7)) << 3) + (cl & 7)] =
          __float2bfloat16(o[ntd][v] * inv);
    }
  }
  #pragma unroll
  for (int e = 0; e < 2; e++) {
    const int rl = e*8 + (l >> 3);
    const int c  = l & 7;
    uint4 vv = *(const uint4*)&Ps[(w*16 + rl)*64 + ((c ^ (rl & 7)) << 3)];
    const int r = qt*64 + w*16 + rl;
    *(uint4*)&ao[((size_t)(b*1024 + r)) * 768 + h*64 + c*8] = vv;
  }
}

// ---------------------------------------------------------------------------
// Plain MFMA NT-GEMM + bias (proj). global_load_lds staging + XCD swizzle.
// ---------------------------------------------------------------------------
__global__ __launch_bounds__(256) void gemm_mfma(
    const bf16* __restrict__ Ab, const bf16* __restrict__ WT,
    const void* __restrict__ bias, void* __restrict__ Cout,
    const int Nd, const int K, const int c_row_off,
    const int* __restrict__ flag, const int bias_mode, const int c_mode)
{
  const int fl = *flag;
  const bool bbf = (bias_mode == 2) ? (fl != 0) : (bias_mode != 0);
  const bool cbf = (c_mode == 2) ? (fl != 0) : (c_mode != 0);

  __shared__ __align__(16) unsigned short As[128*64];
  __shared__ __align__(16) unsigned short Bs[128*64];

  const int tid = threadIdx.x;
  const int l   = tid & 63;
  const int w   = tid >> 6;
  const int wm  = (w & 1) * 64;
  const int wn  = (w >> 1) * 64;

  const int nwg = gridDim.x * gridDim.y;
  const int bid = blockIdx.y * gridDim.x + blockIdx.x;
  const int lb  = xcd_swizzle(bid, nwg);
  const int gy  = gridDim.y;
  const int brow = lb / gy;
  const int bcol = lb - brow * gy;
  const int row0 = brow * 128;
  const int col0 = bcol * 128;

  const int srow = w*8 + (l >> 3);
  const int sch  = (l & 7) ^ (l >> 3);
  const bf16* Ast = Ab + (size_t)(row0 + srow) * K + sch * 8;
  const bf16* Bst = WT + (size_t)(col0 + srow) * K + sch * 8;

  f32x4 acc[4][4] = {};

  for (int k0 = 0; k0 < K; k0 += 64) {
    __syncthreads();
    #pragma unroll
    for (int i = 0; i < 4; i++) {
      gload16(Ast + (size_t)i*32*K + k0, As + (i*32 + w*8)*64);
      gload16(Bst + (size_t)i*32*K + k0, Bs + (i*32 + w*8)*64);
    }
    __syncthreads();
    #pragma unroll
    for (int s = 0; s < 2; s++) {
      bf16x8 af[4], bg[4];
      const int ch = (s*4 + (l >> 4)) ^ (l & 7);
      #pragma unroll
      for (int i = 0; i < 4; i++) {
        const int rowm = wm + i*16 + (l & 15);
        const int rown = wn + i*16 + (l & 15);
        af[i] = *(const bf16x8*)&As[rowm*64 + ch*8];
        bg[i] = *(const bf16x8*)&Bs[rown*64 + ch*8];
      }
      #pragma unroll
      for (int i = 0; i < 4; i++)
        #pragma unroll
        for (int j = 0; j < 4; j++)
          acc[i][j] = __builtin_amdgcn_mfma_f32_16x16x32_bf16(
                          af[i], bg[j], acc[i][j], 0, 0, 0);
    }
  }

  const int cn    = col0 + wn + (l & 15);
  const int rbase = c_row_off + row0 + wm + (l >> 4) * 4;
  #pragma unroll
  for (int j = 0; j < 4; j++) {
    const int col = cn + j*16;
    const float bval = bbf ? tof(((const bf16*)bias)[col])
                           : ((const float*)bias)[col];
    #pragma unroll
    for (int i = 0; i < 4; i++) {
      #pragma unroll
      for (int v = 0; v < 4; v++) {
        const size_t r = (size_t)(rbase + i*16 + v);
        const float val = acc[i][j][v] + bval;
        if (cbf) ((bf16*)Cout)[r * Nd + col] = __float2bfloat16(val);
        else     ((float*)Cout)[r * Nd + col] = val;
      }
    }
  }
}

// ---------------------------------------------------------------------------
// ws: flag(256B) | WqkvT 3.54MB | WprojT 1.18MB |
//     xb | Qp | Kp | Vt | ao  (each CB*1.57MB)
// ---------------------------------------------------------------------------
extern "C" void kernel_launch(void* const* d_in, const int* in_sizes, int n_in,
                              void* d_out, int out_size, void* d_ws, size_t ws_size,
                              hipStream_t stream)
{
  (void)in_sizes; (void)n_in; (void)out_size;
  const void* x     = d_in[0];
  const void* Wqkv  = d_in[1];
  const void* bqkv  = d_in[2];
  const void* Wproj = d_in[3];
  const void* bproj = d_in[4];
  const int*  pos_h = (const int*)d_in[5];
  const int*  pos_w = (const int*)d_in[6];

  int* flag = (int*)d_ws;
  char* p = (char*)d_ws + 256;
  bf16* WqkvT  = (bf16*)p; p += (size_t)QC_ * C_ * 2;
  bf16* WprojT = (bf16*)p; p += (size_t)C_ * C_ * 2;

  const size_t fixed = 256 + (size_t)QC_*C_*2 + (size_t)C_*C_*2;
  const size_t perb  = 5 * (size_t)N_ * C_ * 2;   // xb,Qp,Kp,Vt,ao per batch
  int CB = 16;
  if (ws_size < fixed + 16*perb) CB = 8;
  if (ws_size < fixed + 8*perb)  CB = 4;
  if (ws_size < fixed + 4*perb)  CB = 2;
  if (ws_size < fixed + 2*perb)  CB = 1;
  const int Mc = CB * N_;
  const size_t tsz = (size_t)Mc * C_;

  bf16* xb  = (bf16*)p;
  bf16* Qp  = xb  + tsz;
  bf16* Kp  = Qp  + tsz;
  bf16* Vtb = Kp  + tsz;
  bf16* ao  = Vtb + tsz;

  detect_dtype<<<1, 256, 0, stream>>>((const unsigned*)x, flag);
  wt_cvt<<<dim3(QC_/32, C_/32), 256, 0, stream>>>(Wqkv, WqkvT, C_, QC_, flag);
  wt_cvt<<<dim3(C_/32,  C_/32), 256, 0, stream>>>(Wproj, WprojT, C_, C_, flag);

  for (int c0 = 0; c0 < B_; c0 += CB) {
    const int n4 = Mc * C_ / 4;
    cvt_x<<<(n4 + 255)/256, 256, 0, stream>>>(x, xb, flag, n4, c0 * N_ * C_ / 4);
    gemm_qkv_rope<<<dim3(Mc/128, QC_/128), 256, 0, stream>>>(
        xb, WqkvT, bqkv, Qp, Kp, Vtb, flag,
        pos_h + (size_t)c0*N_, pos_w + (size_t)c0*N_);
    attn_mfma<<<dim3(N_/64, CB*H_), 256, 0, stream>>>(Qp, Kp, Vtb, ao);
    gemm_mfma<<<dim3(Mc/128, C_/128), 256, 0, stream>>>(
        ao, WprojT, bproj, d_out, C_, C_, c0*N_, flag, 2, 2);
  }
}

// Round 4
// 368.688 us; speedup vs baseline: 2.3240x; 1.1782x over previous
//
#include <hip/hip_runtime.h>
#include <hip/hip_bf16.h>

#define B_ 16
#define N_ 1024
#define C_ 768
#define H_ 12
#define HD_ 64
#define QC_ (3*C_)      // 2304

using bf16 = __hip_bfloat16;
using bf16x8 = __attribute__((ext_vector_type(8))) __bf16;
using f32x4  = __attribute__((ext_vector_type(4))) float;

__device__ __forceinline__ float tof(bf16 v){ return __bfloat162float(v); }

// Async global->LDS 16B DMA. LDS dest is wave-uniform base + lane*16 (linear);
// swizzle is applied on the per-lane GLOBAL address (rule #21: linear dest +
// inverse-swizzled source + swizzled read).
__device__ __forceinline__ void gload16(const void* g, void* l) {
  __builtin_amdgcn_global_load_lds(
      (const __attribute__((address_space(1))) unsigned int*)g,
      (__attribute__((address_space(3))) unsigned int*)l, 16, 0, 0);
}

// XCD-aware bijective block swizzle: physical bid -> logical lb such that
// each XCD (bid%8) owns a CONTIGUOUS chunk of logical tile space.
// Requires nwg % 8 == 0 (all our grids satisfy this).
__device__ __forceinline__ int xcd_swizzle(int bid, int nwg) {
  return (bid & 7) * (nwg >> 3) + (bid >> 3);
}

// pack two f32 -> one u32 of 2 bf16 (RNE via __float2bfloat16)
__device__ __forceinline__ unsigned pk2(float a, float b) {
  unsigned ua = (unsigned)__bfloat16_as_ushort(__float2bfloat16(a));
  unsigned ub = (unsigned)__bfloat16_as_ushort(__float2bfloat16(b));
  return ua | (ub << 16);
}

// ---------------------------------------------------------------------------
// Input-dtype detector (1=bf16, 0=fp32) from bits 14:7 of sampled words.
// ---------------------------------------------------------------------------
__global__ __launch_bounds__(256) void detect_dtype(
    const unsigned* __restrict__ x32, int* __restrict__ flag)
{
  __shared__ int cnt;
  if (threadIdx.x == 0) cnt = 0;
  __syncthreads();
  int local = 0;
  #pragma unroll
  for (int i = 0; i < 16; i++) {
    unsigned u = x32[threadIdx.x * 16 + i * 4096];
    unsigned e = (u >> 7) & 0xFF;
    local += (e >= 110 && e <= 140) ? 1 : 0;
  }
  atomicAdd(&cnt, local);
  __syncthreads();
  if (threadIdx.x == 0) *flag = (cnt > 2048) ? 1 : 0;
}

// ---------------------------------------------------------------------------
// Cast x (fp32 or bf16 per flag) -> bf16, 4 elems/thread.
// ---------------------------------------------------------------------------
__global__ __launch_bounds__(256) void cvt_x(
    const void* __restrict__ x, bf16* __restrict__ xb,
    const int* __restrict__ flag, const int n4, const int off4)
{
  const int i = blockIdx.x * 256 + threadIdx.x;
  if (i >= n4) return;
  if (*flag) {
    ((uint2*)xb)[i] = ((const uint2*)x)[off4 + i];
  } else {
    float4 v = ((const float4*)x)[off4 + i];
    xb[i*4+0] = __float2bfloat16(v.x);
    xb[i*4+1] = __float2bfloat16(v.y);
    xb[i*4+2] = __float2bfloat16(v.z);
    xb[i*4+3] = __float2bfloat16(v.w);
  }
}

// ---------------------------------------------------------------------------
// WT[n][k] (bf16) = W[k][n] (dtype per flag). Tiled 32x32 transpose.
// ---------------------------------------------------------------------------
__global__ __launch_bounds__(256) void wt_cvt(
    const void* __restrict__ W, bf16* __restrict__ WT,
    const int K, const int Nd, const int* __restrict__ flag)
{
  __shared__ float t[32][33];
  const int fl = *flag;
  const int n0 = blockIdx.x * 32, k0 = blockIdx.y * 32;
  const int tx = threadIdx.x & 31, ty = threadIdx.x >> 5;   // 32 x 8
  for (int kk = ty; kk < 32; kk += 8) {
    const size_t gi = (size_t)(k0 + kk) * Nd + (n0 + tx);
    t[kk][tx] = fl ? tof(((const bf16*)W)[gi]) : ((const float*)W)[gi];
  }
  __syncthreads();
  for (int nn = ty; nn < 32; nn += 8)
    WT[(size_t)(n0 + nn) * K + (k0 + tx)] = __float2bfloat16(t[tx][nn]);
}

// ---------------------------------------------------------------------------
// Fused qkv GEMM + bias + RoPE + layout scatter. (unchanged, verified)
// ---------------------------------------------------------------------------
__global__ __launch_bounds__(256) void gemm_qkv_rope(
    const bf16* __restrict__ Ab, const bf16* __restrict__ WT,
    const void* __restrict__ bias, bf16* __restrict__ Qp,
    bf16* __restrict__ Kp, bf16* __restrict__ Vtb,
    const int* __restrict__ flag,
    const int* __restrict__ pos_h, const int* __restrict__ pos_w)
{
  const int K = C_;
  const bool bbf = (*flag != 0);

  __shared__ __align__(16) char smem[36864];
  unsigned short* As = (unsigned short*)smem;
  unsigned short* Bs = (unsigned short*)(smem + 16384);

  const int tid = threadIdx.x;
  const int l   = tid & 63;
  const int w   = tid >> 6;
  const int wm  = (w & 1) * 64;
  const int wn  = (w >> 1) * 64;

  const int nwg = gridDim.x * gridDim.y;
  const int bid = blockIdx.y * gridDim.x + blockIdx.x;
  const int lb  = xcd_swizzle(bid, nwg);
  const int gy  = gridDim.y;                 // 18
  const int brow = lb / gy;
  const int bcol = lb - brow * gy;
  const int row0 = brow * 128;
  const int col0 = bcol * 128;

  const int srow = w*8 + (l >> 3);
  const int sch  = (l & 7) ^ (l >> 3);
  const bf16* Ast = Ab + (size_t)(row0 + srow) * K + sch * 8;
  const bf16* Bst = WT + (size_t)(col0 + srow) * K + sch * 8;

  f32x4 acc[4][4] = {};

  for (int k0 = 0; k0 < K; k0 += 64) {
    __syncthreads();                         // prev iter's LDS reads done
    #pragma unroll
    for (int i = 0; i < 4; i++) {
      gload16(Ast + (size_t)i*32*K + k0, As + (i*32 + w*8)*64);
      gload16(Bst + (size_t)i*32*K + k0, Bs + (i*32 + w*8)*64);
    }
    __syncthreads();                         // drains vmcnt -> LDS ready
    #pragma unroll
    for (int s = 0; s < 2; s++) {
      bf16x8 af[4], bg[4];
      const int ch = (s*4 + (l >> 4)) ^ (l & 7);
      #pragma unroll
      for (int i = 0; i < 4; i++) {
        const int rowm = wm + i*16 + (l & 15);
        const int rown = wn + i*16 + (l & 15);
        af[i] = *(const bf16x8*)&As[rowm*64 + ch*8];
        bg[i] = *(const bf16x8*)&Bs[rown*64 + ch*8];
      }
      #pragma unroll
      for (int i = 0; i < 4; i++)
        #pragma unroll
        for (int j = 0; j < 4; j++)
          acc[i][j] = __builtin_amdgcn_mfma_f32_16x16x32_bf16(
                          af[i], bg[j], acc[i][j], 0, 0, 0);
    }
  }

  // ---- fused epilogue ----
  const int colbase = col0 + wn;            // multiple of 64
  const int t   = colbase / 768;            // 0=q 1=k 2=v (block-uniform)
  const int h   = (colbase % 768) >> 6;     // head (wave-uniform)
  const int dd0 = l & 15;
  float bv4[4];
  #pragma unroll
  for (int j = 0; j < 4; j++) {
    const int c = colbase + dd0 + j*16;
    bv4[j] = bbf ? tof(((const bf16*)bias)[c]) : ((const float*)bias)[c];
  }
  const int rb = row0 + wm + (l >> 4) * 4;

  __syncthreads();                           // As/Bs dead for ALL waves
  bf16* Ts = (bf16*)(smem + w * 9216);       // 64 rows x 72 elems (144 B)

  if (t == 2) {
    #pragma unroll
    for (int i = 0; i < 4; i++) {
      #pragma unroll
      for (int v = 0; v < 4; v++) {
        const int nl = i*16 + ((l >> 4) << 2) + v;   // n_local 0..63
        #pragma unroll
        for (int j = 0; j < 4; j++) {
          const int dl = dd0 + j*16;                 // d_local 0..63
          const float y = acc[i][j][v] + bv4[j];
          Ts[dl*72 + (((nl >> 3) ^ (dl & 7)) << 3) + (nl & 7)] =
              __float2bfloat16(y);
        }
      }
    }
  } else {
    const int fi  = dd0 >> 1;
    const float LOG2B = 13.287712379549449f;  // log2(10000)
    const float f1 = exp2f(-LOG2B * (float)fi       * (1.0f/16.0f));
    const float f2 = exp2f(-LOG2B * (float)(fi + 8) * (1.0f/16.0f));
    #pragma unroll
    for (int i = 0; i < 4; i++) {
      #pragma unroll
      for (int v = 0; v < 4; v++) {
        const int r  = rb + i*16 + v;          // chunk-local row (global)
        const int rl = i*16 + (l >> 4)*4 + v;  // row local to wave 0..63
        float y0 = acc[i][0][v] + bv4[0];
        float y1 = acc[i][1][v] + bv4[1];
        float y2 = acc[i][2][v] + bv4[2];
        float y3 = acc[i][3][v] + bv4[3];
        const float ph = (float)pos_h[r];
        const float pw = (float)pos_w[r];
        float s1,c1,s2,c2,s3,c3,s4,c4;
        __sincosf(ph*f1, &s1, &c1);
        __sincosf(ph*f2, &s2, &c2);
        __sincosf(pw*f1, &s3, &c3);
        __sincosf(pw*f2, &s4, &c4);
        float z[4];
        z[0] = y0*c1 - y1*s1;
        z[1] = y1*c2 + y0*s2;
        z[2] = y2*c3 - y3*s3;
        z[3] = y3*c4 + y2*s4;
        if (t == 0) { z[0]*=0.125f; z[1]*=0.125f; z[2]*=0.125f; z[3]*=0.125f; }
        #pragma unroll
        for (int j = 0; j < 4; j++) {
          const int cl = dd0 + j*16;           // col local 0..63
          Ts[rl*72 + (((cl >> 3) ^ (rl & 7)) << 3) + (cl & 7)] =
              __float2bfloat16(z[j]);
        }
      }
    }
  }
  __syncthreads();                           // ds_writes visible (in-block)

  if (t == 2) {
    const int n0 = (row0 + wm) & 1023;
    const int bp = (row0 + wm) >> 10;
    const size_t gbase = (size_t)(bp*12 + h) * 65536;   // [bh][64][1024]
    #pragma unroll
    for (int dr = 0; dr < 8; dr++) {
      const int dl = dr*8 + (l >> 3);
      const int c  = l & 7;                  // logical 8-elem chunk
      uint4 vv = *(const uint4*)&Ts[dl*72 + ((c ^ (dl & 7)) << 3)];
      *(uint4*)&Vtb[gbase + (size_t)dl*1024 + n0 + c*8] = vv;
    }
  } else {
    bf16* dst = (t == 0) ? Qp : Kp;
    const int rg0 = row0 + wm;               // 64-row block, one bp
    const int bp  = rg0 >> 10;
    const int nb  = rg0 & 1023;
    const size_t gbase = (size_t)(bp*12 + h) * 65536;   // [bh][1024][64]
    #pragma unroll
    for (int dr = 0; dr < 8; dr++) {
      const int rl = dr*8 + (l >> 3);
      const int c  = l & 7;
      uint4 vv = *(const uint4*)&Ts[rl*72 + ((c ^ (rl & 7)) << 3)];
      *(uint4*)&dst[gbase + (size_t)(nb + rl)*64 + c*8] = vv;
    }
  }
}

// ---------------------------------------------------------------------------
// MFMA flash attention. Round-4 changes:
//  * swapped QK^T: mfma(K,Q) -> S^T layout, each lane owns ONE q-row
//    (q = w*16 + (l&15)); row reduce = in-lane + 2 shfl (was 16 shfl).
//  * m_i/l_i scalar per lane; defer-max (THR=8) skips alpha+o-rescale.
//  * P stores: 4x ds_write_b64 packed bf16 (was 16x ds_write_b16).
// PV, staging (global_load_lds), epilogue unchanged.
// ---------------------------------------------------------------------------
__global__ __launch_bounds__(256) void attn_mfma(
    const bf16* __restrict__ Qp, const bf16* __restrict__ Kp,
    const bf16* __restrict__ Vtb, bf16* __restrict__ ao)
{
  __shared__ __align__(16) bf16 Qs[64*64];
  __shared__ __align__(16) bf16 Ks[64*64];
  __shared__ __align__(16) bf16 Vs[64*64];   // V^T tile: rows=d, cols=kk
  __shared__ __align__(16) bf16 Ps[64*64];   // P, per-wave 16-row regions
  const int tid = threadIdx.x;
  const int l   = tid & 63;
  const int w   = tid >> 6;

  const int nwg = gridDim.x * gridDim.y;
  const int bid = blockIdx.y * gridDim.x + blockIdx.x;
  const int lb  = xcd_swizzle(bid, nwg);     // bh-major logical order
  const int qt  = lb & 15;                   // 0..15
  const int bh  = lb >> 4;                   // chunk-local b*12 + h
  const size_t base = (size_t)bh * 65536;

  const int srow = w*8 + (l >> 3);
  const int sch  = (l & 7) ^ (l >> 3);
  const bf16* Qst = Qp  + base + (size_t)(qt*64 + srow)*64 + sch*8;
  const bf16* Kst = Kp  + base + (size_t)srow*64   + sch*8;
  const bf16* Vst = Vtb + base + (size_t)srow*1024 + sch*8;

  #pragma unroll
  for (int i = 0; i < 2; i++)
    gload16(Qst + (size_t)i*32*64, Qs + (i*32 + w*8)*64);
  __syncthreads();                           // drains vmcnt

  bf16x8 af[2];
  {
    const int row = w*16 + (l & 15);
    #pragma unroll
    for (int s = 0; s < 2; s++) {
      const int ch = (s*4 + (l >> 4)) ^ (row & 7);
      af[s] = *(const bf16x8*)&Qs[row*64 + ch*8];
    }
  }

  const float LOG2E = 1.4426950408889634f;
  float m_i = -3.0e38f, l_i = 0.f;           // per-lane, q = w*16 + (l&15)
  f32x4 o[4] = {};                           // q-local = (l>>4)*4+v, d = ntd*16+(l&15)

  const int g    = l >> 4;                   // lane quarter
  const int qrow = w*16 + (l & 15);          // this lane's q-row (local)

  for (int kt = 0; kt < 16; kt++) {
    __syncthreads();                         // prev iter's LDS reads done
    #pragma unroll
    for (int i = 0; i < 2; i++) {
      gload16(Kst + (size_t)(kt*64 + i*32)*64, Ks + (i*32 + w*8)*64);
      gload16(Vst + (size_t)i*32*1024 + kt*64, Vs + (i*32 + w*8)*64);
    }
    __syncthreads();                         // drains vmcnt -> tiles ready

    // ---- S^T = K . Q^T : s[nt][v] = S[k = nt*16 + 4g + v][q = qrow] ----
    f32x4 s[4];
    #pragma unroll
    for (int nt = 0; nt < 4; nt++) {
      f32x4 a = {};
      const int nrow = nt*16 + (l & 15);
      #pragma unroll
      for (int ss = 0; ss < 2; ss++) {
        const int ch = (ss*4 + (l >> 4)) ^ (nrow & 7);
        bf16x8 bg = *(const bf16x8*)&Ks[nrow*64 + ch*8];
        a = __builtin_amdgcn_mfma_f32_16x16x32_bf16(bg, af[ss], a, 0, 0, 0);
      }
      s[nt] = a;
    }

    // ---- online softmax, per-lane q-row ----
    float mloc = s[0][0];
    #pragma unroll
    for (int nt = 0; nt < 4; nt++)
      #pragma unroll
      for (int v = 0; v < 4; v++)
        mloc = fmaxf(mloc, s[nt][v]);
    mloc = fmaxf(mloc, __shfl_xor(mloc, 16));
    const float m0 = fmaxf(mloc, __shfl_xor(mloc, 32));

    if (!__all(m0 - m_i <= 8.0f)) {          // rescale (rare after tile 0)
      const float mx = fmaxf(m_i, m0);
      const float alpha = exp2f((m_i - mx) * LOG2E);
      l_i *= alpha;
      m_i = mx;
      float a_o[4];
      #pragma unroll
      for (int v = 0; v < 4; v++)            // alpha for o's q-local = 4g+v
        a_o[v] = __shfl(alpha, (l & 48) | ((g << 2) + v));
      #pragma unroll
      for (int nt = 0; nt < 4; nt++)
        #pragma unroll
        for (int v = 0; v < 4; v++)
          o[nt][v] *= a_o[v];
    }

    float r = 0.f;
    #pragma unroll
    for (int nt = 0; nt < 4; nt++)
      #pragma unroll
      for (int v = 0; v < 4; v++) {
        const float p = exp2f((s[nt][v] - m_i) * LOG2E);
        s[nt][v] = p;
        r += p;
      }
    r += __shfl_xor(r, 16);
    r += __shfl_xor(r, 32);
    l_i += r;

    // ---- P^T -> Ps as P[q][k]: 4 consecutive k per lane -> b64 stores ----
    #pragma unroll
    for (int nt = 0; nt < 4; nt++) {
      const int k0 = nt*16 + (g << 2);       // 4 consecutive k
      const int ch = (k0 >> 3) ^ (qrow & 7);
      uint2 uu;
      uu.x = pk2(s[nt][0], s[nt][1]);
      uu.y = pk2(s[nt][2], s[nt][3]);
      *(uint2*)&Ps[qrow*64 + ch*8 + (k0 & 7)] = uu;
    }

    // ---- PV (unchanged): o[q-local][d] += P[q][k] * V^T[d][k] ----
    #pragma unroll
    for (int ss = 0; ss < 2; ss++) {
      const int prow = w*16 + (l & 15);
      const int pch  = (ss*4 + (l >> 4)) ^ (prow & 7);
      bf16x8 pa = *(const bf16x8*)&Ps[prow*64 + pch*8];
      #pragma unroll
      for (int ntd = 0; ntd < 4; ntd++) {
        const int drow = ntd*16 + (l & 15);
        const int vch  = (ss*4 + (l >> 4)) ^ (drow & 7);
        bf16x8 vb = *(const bf16x8*)&Vs[drow*64 + vch*8];
        o[ntd] = __builtin_amdgcn_mfma_f32_16x16x32_bf16(pa, vb, o[ntd], 0,0,0);
      }
    }
  }

  // ---- epilogue: transpose 1/l_i into o layout, re-tile through Ps,
  //      16B coalesced stores ----
  const int b = bh / 12, h = bh - b*12;
  const float inv = 1.0f / l_i;              // q = l&15 layout
  float inv_o[4];
  #pragma unroll
  for (int v = 0; v < 4; v++)
    inv_o[v] = __shfl(inv, (l & 48) | ((g << 2) + v));
  #pragma unroll
  for (int v = 0; v < 4; v++) {
    const int rl = g*4 + v;                  // 0..15 local row
    #pragma unroll
    for (int ntd = 0; ntd < 4; ntd++) {
      const int cl = ntd*16 + (l & 15);      // 0..63 local col
      Ps[(w*16 + rl)*64 + (((cl >> 3) ^ (rl & 7)) << 3) + (cl & 7)] =
          __float2bfloat16(o[ntd][v] * inv_o[v]);
    }
  }
  #pragma unroll
  for (int e = 0; e < 2; e++) {
    const int rl = e*8 + (l >> 3);
    const int c  = l & 7;
    uint4 vv = *(const uint4*)&Ps[(w*16 + rl)*64 + ((c ^ (rl & 7)) << 3)];
    const int r = qt*64 + w*16 + rl;
    *(uint4*)&ao[((size_t)(b*1024 + r)) * 768 + h*64 + c*8] = vv;
  }
}

// ---------------------------------------------------------------------------
// Plain MFMA NT-GEMM + bias (proj). global_load_lds staging + XCD swizzle.
// ---------------------------------------------------------------------------
__global__ __launch_bounds__(256) void gemm_mfma(
    const bf16* __restrict__ Ab, const bf16* __restrict__ WT,
    const void* __restrict__ bias, void* __restrict__ Cout,
    const int Nd, const int K, const int c_row_off,
    const int* __restrict__ flag, const int bias_mode, const int c_mode)
{
  const int fl = *flag;
  const bool bbf = (bias_mode == 2) ? (fl != 0) : (bias_mode != 0);
  const bool cbf = (c_mode == 2) ? (fl != 0) : (c_mode != 0);

  __shared__ __align__(16) unsigned short As[128*64];
  __shared__ __align__(16) unsigned short Bs[128*64];

  const int tid = threadIdx.x;
  const int l   = tid & 63;
  const int w   = tid >> 6;
  const int wm  = (w & 1) * 64;
  const int wn  = (w >> 1) * 64;

  const int nwg = gridDim.x * gridDim.y;
  const int bid = blockIdx.y * gridDim.x + blockIdx.x;
  const int lb  = xcd_swizzle(bid, nwg);
  const int gy  = gridDim.y;
  const int brow = lb / gy;
  const int bcol = lb - brow * gy;
  const int row0 = brow * 128;
  const int col0 = bcol * 128;

  const int srow = w*8 + (l >> 3);
  const int sch  = (l & 7) ^ (l >> 3);
  const bf16* Ast = Ab + (size_t)(row0 + srow) * K + sch * 8;
  const bf16* Bst = WT + (size_t)(col0 + srow) * K + sch * 8;

  f32x4 acc[4][4] = {};

  for (int k0 = 0; k0 < K; k0 += 64) {
    __syncthreads();
    #pragma unroll
    for (int i = 0; i < 4; i++) {
      gload16(Ast + (size_t)i*32*K + k0, As + (i*32 + w*8)*64);
      gload16(Bst + (size_t)i*32*K + k0, Bs + (i*32 + w*8)*64);
    }
    __syncthreads();
    #pragma unroll
    for (int s = 0; s < 2; s++) {
      bf16x8 af[4], bg[4];
      const int ch = (s*4 + (l >> 4)) ^ (l & 7);
      #pragma unroll
      for (int i = 0; i < 4; i++) {
        const int rowm = wm + i*16 + (l & 15);
        const int rown = wn + i*16 + (l & 15);
        af[i] = *(const bf16x8*)&As[rowm*64 + ch*8];
        bg[i] = *(const bf16x8*)&Bs[rown*64 + ch*8];
      }
      #pragma unroll
      for (int i = 0; i < 4; i++)
        #pragma unroll
        for (int j = 0; j < 4; j++)
          acc[i][j] = __builtin_amdgcn_mfma_f32_16x16x32_bf16(
                          af[i], bg[j], acc[i][j], 0, 0, 0);
    }
  }

  const int cn    = col0 + wn + (l & 15);
  const int rbase = c_row_off + row0 + wm + (l >> 4) * 4;
  #pragma unroll
  for (int j = 0; j < 4; j++) {
    const int col = cn + j*16;
    const float bval = bbf ? tof(((const bf16*)bias)[col])
                           : ((const float*)bias)[col];
    #pragma unroll
    for (int i = 0; i < 4; i++) {
      #pragma unroll
      for (int v = 0; v < 4; v++) {
        const size_t r = (size_t)(rbase + i*16 + v);
        const float val = acc[i][j][v] + bval;
        if (cbf) ((bf16*)Cout)[r * Nd + col] = __float2bfloat16(val);
        else     ((float*)Cout)[r * Nd + col] = val;
      }
    }
  }
}

// ---------------------------------------------------------------------------
// ws: flag(256B) | WqkvT 3.54MB | WprojT 1.18MB |
//     xb | Qp | Kp | Vt | ao  (each CB*1.57MB)
// ---------------------------------------------------------------------------
extern "C" void kernel_launch(void* const* d_in, const int* in_sizes, int n_in,
                              void* d_out, int out_size, void* d_ws, size_t ws_size,
                              hipStream_t stream)
{
  (void)in_sizes; (void)n_in; (void)out_size;
  const void* x     = d_in[0];
  const void* Wqkv  = d_in[1];
  const void* bqkv  = d_in[2];
  const void* Wproj = d_in[3];
  const void* bproj = d_in[4];
  const int*  pos_h = (const int*)d_in[5];
  const int*  pos_w = (const int*)d_in[6];

  int* flag = (int*)d_ws;
  char* p = (char*)d_ws + 256;
  bf16* WqkvT  = (bf16*)p; p += (size_t)QC_ * C_ * 2;
  bf16* WprojT = (bf16*)p; p += (size_t)C_ * C_ * 2;

  const size_t fixed = 256 + (size_t)QC_*C_*2 + (size_t)C_*C_*2;
  const size_t perb  = 5 * (size_t)N_ * C_ * 2;   // xb,Qp,Kp,Vt,ao per batch
  int CB = 16;
  if (ws_size < fixed + 16*perb) CB = 8;
  if (ws_size < fixed + 8*perb)  CB = 4;
  if (ws_size < fixed + 4*perb)  CB = 2;
  if (ws_size < fixed + 2*perb)  CB = 1;
  const int Mc = CB * N_;
  const size_t tsz = (size_t)Mc * C_;

  bf16* xb  = (bf16*)p;
  bf16* Qp  = xb  + tsz;
  bf16* Kp  = Qp  + tsz;
  bf16* Vtb = Kp  + tsz;
  bf16* ao  = Vtb + tsz;

  detect_dtype<<<1, 256, 0, stream>>>((const unsigned*)x, flag);
  wt_cvt<<<dim3(QC_/32, C_/32), 256, 0, stream>>>(Wqkv, WqkvT, C_, QC_, flag);
  wt_cvt<<<dim3(C_/32,  C_/32), 256, 0, stream>>>(Wproj, WprojT, C_, C_, flag);

  for (int c0 = 0; c0 < B_; c0 += CB) {
    const int n4 = Mc * C_ / 4;
    cvt_x<<<(n4 + 255)/256, 256, 0, stream>>>(x, xb, flag, n4, c0 * N_ * C_ / 4);
    gemm_qkv_rope<<<dim3(Mc/128, QC_/128), 256, 0, stream>>>(
        xb, WqkvT, bqkv, Qp, Kp, Vtb, flag,
        pos_h + (size_t)c0*N_, pos_w + (size_t)c0*N_);
    attn_mfma<<<dim3(N_/64, CB*H_), 256, 0, stream>>>(Qp, Kp, Vtb, ao);
    gemm_mfma<<<dim3(Mc/128, C_/128), 256, 0, stream>>>(
        ao, WprojT, bproj, d_out, C_, C_, c0*N_, flag, 2, 2);
  }
}

// Round 5
// 359.392 us; speedup vs baseline: 2.3842x; 1.0259x over previous
//
#include <hip/hip_runtime.h>
#include <hip/hip_bf16.h>

#define B_ 16
#define N_ 1024
#define C_ 768
#define H_ 12
#define HD_ 64
#define QC_ (3*C_)      // 2304

using bf16 = __hip_bfloat16;
using bf16x8 = __attribute__((ext_vector_type(8))) __bf16;
using f32x4  = __attribute__((ext_vector_type(4))) float;

__device__ __forceinline__ float tof(bf16 v){ return __bfloat162float(v); }

// Async global->LDS 16B DMA. LDS dest is wave-uniform base + lane*16 (linear);
// swizzle is applied on the per-lane GLOBAL address (rule #21: linear dest +
// inverse-swizzled source + swizzled read).
__device__ __forceinline__ void gload16(const void* g, void* l) {
  __builtin_amdgcn_global_load_lds(
      (const __attribute__((address_space(1))) unsigned int*)g,
      (__attribute__((address_space(3))) unsigned int*)l, 16, 0, 0);
}

// XCD-aware bijective block swizzle: physical bid -> logical lb such that
// each XCD (bid%8) owns a CONTIGUOUS chunk of logical tile space.
// Requires nwg % 8 == 0 (all our grids satisfy this).
__device__ __forceinline__ int xcd_swizzle(int bid, int nwg) {
  return (bid & 7) * (nwg >> 3) + (bid >> 3);
}

// pack two f32 -> one u32 of 2 bf16 (compiler emits v_cvt_pk_bf16_f32)
__device__ __forceinline__ unsigned pk2(float a, float b) {
  unsigned ua = (unsigned)__bfloat16_as_ushort(__float2bfloat16(a));
  unsigned ub = (unsigned)__bfloat16_as_ushort(__float2bfloat16(b));
  return ua | (ub << 16);
}

// ---------------------------------------------------------------------------
// Input-dtype detector (1=bf16, 0=fp32) from bits 14:7 of sampled words.
// ---------------------------------------------------------------------------
__global__ __launch_bounds__(256) void detect_dtype(
    const unsigned* __restrict__ x32, int* __restrict__ flag)
{
  __shared__ int cnt;
  if (threadIdx.x == 0) cnt = 0;
  __syncthreads();
  int local = 0;
  #pragma unroll
  for (int i = 0; i < 16; i++) {
    unsigned u = x32[threadIdx.x * 16 + i * 4096];
    unsigned e = (u >> 7) & 0xFF;
    local += (e >= 110 && e <= 140) ? 1 : 0;
  }
  atomicAdd(&cnt, local);
  __syncthreads();
  if (threadIdx.x == 0) *flag = (cnt > 2048) ? 1 : 0;
}

// ---------------------------------------------------------------------------
// Cast x (fp32 or bf16 per flag) -> bf16, 4 elems/thread.
// ---------------------------------------------------------------------------
__global__ __launch_bounds__(256) void cvt_x(
    const void* __restrict__ x, bf16* __restrict__ xb,
    const int* __restrict__ flag, const int n4, const int off4)
{
  const int i = blockIdx.x * 256 + threadIdx.x;
  if (i >= n4) return;
  if (*flag) {
    ((uint2*)xb)[i] = ((const uint2*)x)[off4 + i];
  } else {
    float4 v = ((const float4*)x)[off4 + i];
    xb[i*4+0] = __float2bfloat16(v.x);
    xb[i*4+1] = __float2bfloat16(v.y);
    xb[i*4+2] = __float2bfloat16(v.z);
    xb[i*4+3] = __float2bfloat16(v.w);
  }
}

// ---------------------------------------------------------------------------
// WT[n][k] (bf16) = W[k][n] (dtype per flag). Tiled 32x32 transpose.
// ---------------------------------------------------------------------------
__global__ __launch_bounds__(256) void wt_cvt(
    const void* __restrict__ W, bf16* __restrict__ WT,
    const int K, const int Nd, const int* __restrict__ flag)
{
  __shared__ float t[32][33];
  const int fl = *flag;
  const int n0 = blockIdx.x * 32, k0 = blockIdx.y * 32;
  const int tx = threadIdx.x & 31, ty = threadIdx.x >> 5;   // 32 x 8
  for (int kk = ty; kk < 32; kk += 8) {
    const size_t gi = (size_t)(k0 + kk) * Nd + (n0 + tx);
    t[kk][tx] = fl ? tof(((const bf16*)W)[gi]) : ((const float*)W)[gi];
  }
  __syncthreads();
  for (int nn = ty; nn < 32; nn += 8)
    WT[(size_t)(n0 + nn) * K + (k0 + tx)] = __float2bfloat16(t[tx][nn]);
}

// ---------------------------------------------------------------------------
// Fused qkv GEMM + bias + RoPE + layout scatter.
// Q is scaled by 0.125 * log2(e) so attention S arrives in log2 domain
// (exp2 needs no multiply).
// ---------------------------------------------------------------------------
__global__ __launch_bounds__(256) void gemm_qkv_rope(
    const bf16* __restrict__ Ab, const bf16* __restrict__ WT,
    const void* __restrict__ bias, bf16* __restrict__ Qp,
    bf16* __restrict__ Kp, bf16* __restrict__ Vtb,
    const int* __restrict__ flag,
    const int* __restrict__ pos_h, const int* __restrict__ pos_w)
{
  const int K = C_;
  const bool bbf = (*flag != 0);

  __shared__ __align__(16) char smem[36864];
  unsigned short* As = (unsigned short*)smem;
  unsigned short* Bs = (unsigned short*)(smem + 16384);

  const int tid = threadIdx.x;
  const int l   = tid & 63;
  const int w   = tid >> 6;
  const int wm  = (w & 1) * 64;
  const int wn  = (w >> 1) * 64;

  const int nwg = gridDim.x * gridDim.y;
  const int bid = blockIdx.y * gridDim.x + blockIdx.x;
  const int lb  = xcd_swizzle(bid, nwg);
  const int gy  = gridDim.y;                 // 18
  const int brow = lb / gy;
  const int bcol = lb - brow * gy;
  const int row0 = brow * 128;
  const int col0 = bcol * 128;

  const int srow = w*8 + (l >> 3);
  const int sch  = (l & 7) ^ (l >> 3);
  const bf16* Ast = Ab + (size_t)(row0 + srow) * K + sch * 8;
  const bf16* Bst = WT + (size_t)(col0 + srow) * K + sch * 8;

  f32x4 acc[4][4] = {};

  for (int k0 = 0; k0 < K; k0 += 64) {
    __syncthreads();                         // prev iter's LDS reads done
    #pragma unroll
    for (int i = 0; i < 4; i++) {
      gload16(Ast + (size_t)i*32*K + k0, As + (i*32 + w*8)*64);
      gload16(Bst + (size_t)i*32*K + k0, Bs + (i*32 + w*8)*64);
    }
    __syncthreads();                         // drains vmcnt -> LDS ready
    #pragma unroll
    for (int s = 0; s < 2; s++) {
      bf16x8 af[4], bg[4];
      const int ch = (s*4 + (l >> 4)) ^ (l & 7);
      #pragma unroll
      for (int i = 0; i < 4; i++) {
        const int rowm = wm + i*16 + (l & 15);
        const int rown = wn + i*16 + (l & 15);
        af[i] = *(const bf16x8*)&As[rowm*64 + ch*8];
        bg[i] = *(const bf16x8*)&Bs[rown*64 + ch*8];
      }
      #pragma unroll
      for (int i = 0; i < 4; i++)
        #pragma unroll
        for (int j = 0; j < 4; j++)
          acc[i][j] = __builtin_amdgcn_mfma_f32_16x16x32_bf16(
                          af[i], bg[j], acc[i][j], 0, 0, 0);
    }
  }

  // ---- fused epilogue ----
  const int colbase = col0 + wn;            // multiple of 64
  const int t   = colbase / 768;            // 0=q 1=k 2=v (block-uniform)
  const int h   = (colbase % 768) >> 6;     // head (wave-uniform)
  const int dd0 = l & 15;
  float bv4[4];
  #pragma unroll
  for (int j = 0; j < 4; j++) {
    const int c = colbase + dd0 + j*16;
    bv4[j] = bbf ? tof(((const bf16*)bias)[c]) : ((const float*)bias)[c];
  }
  const int rb = row0 + wm + (l >> 4) * 4;

  __syncthreads();                           // As/Bs dead for ALL waves
  bf16* Ts = (bf16*)(smem + w * 9216);       // 64 rows x 72 elems (144 B)

  if (t == 2) {
    #pragma unroll
    for (int i = 0; i < 4; i++) {
      #pragma unroll
      for (int v = 0; v < 4; v++) {
        const int nl = i*16 + ((l >> 4) << 2) + v;   // n_local 0..63
        #pragma unroll
        for (int j = 0; j < 4; j++) {
          const int dl = dd0 + j*16;                 // d_local 0..63
          const float y = acc[i][j][v] + bv4[j];
          Ts[dl*72 + (((nl >> 3) ^ (dl & 7)) << 3) + (nl & 7)] =
              __float2bfloat16(y);
        }
      }
    }
  } else {
    const int fi  = dd0 >> 1;
    const float LOG2B = 13.287712379549449f;  // log2(10000)
    const float f1 = exp2f(-LOG2B * (float)fi       * (1.0f/16.0f));
    const float f2 = exp2f(-LOG2B * (float)(fi + 8) * (1.0f/16.0f));
    #pragma unroll
    for (int i = 0; i < 4; i++) {
      #pragma unroll
      for (int v = 0; v < 4; v++) {
        const int r  = rb + i*16 + v;          // chunk-local row (global)
        const int rl = i*16 + (l >> 4)*4 + v;  // row local to wave 0..63
        float y0 = acc[i][0][v] + bv4[0];
        float y1 = acc[i][1][v] + bv4[1];
        float y2 = acc[i][2][v] + bv4[2];
        float y3 = acc[i][3][v] + bv4[3];
        const float ph = (float)pos_h[r];
        const float pw = (float)pos_w[r];
        float s1,c1,s2,c2,s3,c3,s4,c4;
        __sincosf(ph*f1, &s1, &c1);
        __sincosf(ph*f2, &s2, &c2);
        __sincosf(pw*f1, &s3, &c3);
        __sincosf(pw*f2, &s4, &c4);
        float z[4];
        z[0] = y0*c1 - y1*s1;
        z[1] = y1*c2 + y0*s2;
        z[2] = y2*c3 - y3*s3;
        z[3] = y3*c4 + y2*s4;
        if (t == 0) {
          const float QS = 0.18033688011112042f;   // 0.125 * log2(e)
          z[0]*=QS; z[1]*=QS; z[2]*=QS; z[3]*=QS;
        }
        #pragma unroll
        for (int j = 0; j < 4; j++) {
          const int cl = dd0 + j*16;           // col local 0..63
          Ts[rl*72 + (((cl >> 3) ^ (rl & 7)) << 3) + (cl & 7)] =
              __float2bfloat16(z[j]);
        }
      }
    }
  }
  __syncthreads();                           // ds_writes visible (in-block)

  if (t == 2) {
    const int n0 = (row0 + wm) & 1023;
    const int bp = (row0 + wm) >> 10;
    const size_t gbase = (size_t)(bp*12 + h) * 65536;   // [bh][64][1024]
    #pragma unroll
    for (int dr = 0; dr < 8; dr++) {
      const int dl = dr*8 + (l >> 3);
      const int c  = l & 7;                  // logical 8-elem chunk
      uint4 vv = *(const uint4*)&Ts[dl*72 + ((c ^ (dl & 7)) << 3)];
      *(uint4*)&Vtb[gbase + (size_t)dl*1024 + n0 + c*8] = vv;
    }
  } else {
    bf16* dst = (t == 0) ? Qp : Kp;
    const int rg0 = row0 + wm;               // 64-row block, one bp
    const int bp  = rg0 >> 10;
    const int nb  = rg0 & 1023;
    const size_t gbase = (size_t)(bp*12 + h) * 65536;   // [bh][1024][64]
    #pragma unroll
    for (int dr = 0; dr < 8; dr++) {
      const int rl = dr*8 + (l >> 3);
      const int c  = l & 7;
      uint4 vv = *(const uint4*)&Ts[rl*72 + ((c ^ (rl & 7)) << 3)];
      *(uint4*)&dst[gbase + (size_t)(nb + rl)*64 + c*8] = vv;
    }
  }
}

// ---------------------------------------------------------------------------
// MFMA flash attention. Round-5 changes:
//  * S arrives pre-scaled by log2(e): exp2 arg is a bare subtract.
//  * Row-sum l via ones-MFMA on the PV A-fragment -> l_acc lands directly
//    in o layout (kills 16 adds + 2 shfl per iter + final transpose).
//  * max via v_max3-friendly fmax triples.
//  * Ps overlays Qs (Q is register-resident after prologue): LDS 24 KB.
//  * s_setprio(1) around MFMA clusters (T5; attn-positive per m191).
// ---------------------------------------------------------------------------
__global__ __launch_bounds__(256) void attn_mfma(
    const bf16* __restrict__ Qp, const bf16* __restrict__ Kp,
    const bf16* __restrict__ Vtb, bf16* __restrict__ ao)
{
  __shared__ __align__(16) bf16 QPs[64*64];  // Qs (prologue) then Ps
  __shared__ __align__(16) bf16 Ks[64*64];
  __shared__ __align__(16) bf16 Vs[64*64];   // V^T tile: rows=d, cols=kk
  bf16* Qs = QPs;
  bf16* Ps = QPs;
  const int tid = threadIdx.x;
  const int l   = tid & 63;
  const int w   = tid >> 6;

  const int nwg = gridDim.x * gridDim.y;
  const int bid = blockIdx.y * gridDim.x + blockIdx.x;
  const int lb  = xcd_swizzle(bid, nwg);     // bh-major logical order
  const int qt  = lb & 15;                   // 0..15
  const int bh  = lb >> 4;                   // chunk-local b*12 + h
  const size_t base = (size_t)bh * 65536;

  const int srow = w*8 + (l >> 3);
  const int sch  = (l & 7) ^ (l >> 3);
  const bf16* Qst = Qp  + base + (size_t)(qt*64 + srow)*64 + sch*8;
  const bf16* Kst = Kp  + base + (size_t)srow*64   + sch*8;
  const bf16* Vst = Vtb + base + (size_t)srow*1024 + sch*8;

  #pragma unroll
  for (int i = 0; i < 2; i++)
    gload16(Qst + (size_t)i*32*64, Qs + (i*32 + w*8)*64);
  __syncthreads();                           // drains vmcnt

  bf16x8 af[2];
  {
    const int row = w*16 + (l & 15);
    #pragma unroll
    for (int s = 0; s < 2; s++) {
      const int ch = (s*4 + (l >> 4)) ^ (row & 7);
      af[s] = *(const bf16x8*)&Qs[row*64 + ch*8];
    }
  }

  bf16x8 ones;
  #pragma unroll
  for (int i = 0; i < 8; i++) ones[i] = (__bf16)1.0f;

  float m_i = -3.0e38f;                      // per-lane, q = w*16 + (l&15)
  f32x4 l_acc = {};                          // denominators, o layout
  f32x4 o[4] = {};                           // q-local=(l>>4)*4+v, d=ntd*16+(l&15)

  const int g    = l >> 4;                   // lane quarter
  const int qrow = w*16 + (l & 15);          // this lane's q-row (local)

  for (int kt = 0; kt < 16; kt++) {
    __syncthreads();                         // prev iter's LDS reads done
    #pragma unroll
    for (int i = 0; i < 2; i++) {
      gload16(Kst + (size_t)(kt*64 + i*32)*64, Ks + (i*32 + w*8)*64);
      gload16(Vst + (size_t)i*32*1024 + kt*64, Vs + (i*32 + w*8)*64);
    }
    __syncthreads();                         // drains vmcnt -> tiles ready

    // ---- S^T = K . Q^T : s[nt][v] = S[k = nt*16 + 4g + v][q = qrow] ----
    f32x4 s[4];
    __builtin_amdgcn_s_setprio(1);
    #pragma unroll
    for (int nt = 0; nt < 4; nt++) {
      f32x4 a = {};
      const int nrow = nt*16 + (l & 15);
      #pragma unroll
      for (int ss = 0; ss < 2; ss++) {
        const int ch = (ss*4 + (l >> 4)) ^ (nrow & 7);
        bf16x8 bg = *(const bf16x8*)&Ks[nrow*64 + ch*8];
        a = __builtin_amdgcn_mfma_f32_16x16x32_bf16(bg, af[ss], a, 0, 0, 0);
      }
      s[nt] = a;
    }
    __builtin_amdgcn_s_setprio(0);

    // ---- online softmax (log2 domain), per-lane q-row ----
    float a0 = fmaxf(fmaxf(s[0][0], s[0][1]), s[0][2]);
    float a1 = fmaxf(fmaxf(s[0][3], s[1][0]), s[1][1]);
    float a2 = fmaxf(fmaxf(s[1][2], s[1][3]), s[2][0]);
    float a3 = fmaxf(fmaxf(s[2][1], s[2][2]), s[2][3]);
    float a4 = fmaxf(fmaxf(s[3][0], s[3][1]), s[3][2]);
    float b0 = fmaxf(fmaxf(a0, a1), a2);
    float b1 = fmaxf(fmaxf(a3, a4), s[3][3]);
    float mloc = fmaxf(b0, b1);
    mloc = fmaxf(mloc, __shfl_xor(mloc, 16));
    const float m0 = fmaxf(mloc, __shfl_xor(mloc, 32));

    if (!__all(m0 - m_i <= 8.0f)) {          // rescale (rare after tile 0)
      const float mx = fmaxf(m_i, m0);
      const float alpha = exp2f(m_i - mx);
      m_i = mx;
      float a_o[4];
      #pragma unroll
      for (int v = 0; v < 4; v++)            // alpha for o's q-local = 4g+v
        a_o[v] = __shfl(alpha, (l & 48) | ((g << 2) + v));
      #pragma unroll
      for (int v = 0; v < 4; v++) {
        l_acc[v] *= a_o[v];
        #pragma unroll
        for (int nt = 0; nt < 4; nt++) o[nt][v] *= a_o[v];
      }
    }

    // ---- P = 2^(S - m), pack to bf16, b64 store into Ps ----
    #pragma unroll
    for (int nt = 0; nt < 4; nt++) {
      const float p0 = exp2f(s[nt][0] - m_i);
      const float p1 = exp2f(s[nt][1] - m_i);
      const float p2 = exp2f(s[nt][2] - m_i);
      const float p3 = exp2f(s[nt][3] - m_i);
      const int k0 = nt*16 + (g << 2);       // 4 consecutive k
      const int ch = (k0 >> 3) ^ (qrow & 7);
      uint2 uu;
      uu.x = pk2(p0, p1);
      uu.y = pk2(p2, p3);
      *(uint2*)&Ps[qrow*64 + ch*8 + (k0 & 7)] = uu;
    }

    // ---- PV + l: o[q][d] += P[q][k] V^T[d][k]; l_acc += P . 1 ----
    __builtin_amdgcn_s_setprio(1);
    #pragma unroll
    for (int ss = 0; ss < 2; ss++) {
      const int pch  = (ss*4 + g) ^ (qrow & 7);
      bf16x8 pa = *(const bf16x8*)&Ps[qrow*64 + pch*8];
      l_acc = __builtin_amdgcn_mfma_f32_16x16x32_bf16(pa, ones, l_acc, 0,0,0);
      #pragma unroll
      for (int ntd = 0; ntd < 4; ntd++) {
        const int drow = ntd*16 + (l & 15);
        const int vch  = (ss*4 + (l >> 4)) ^ (drow & 7);
        bf16x8 vb = *(const bf16x8*)&Vs[drow*64 + vch*8];
        o[ntd] = __builtin_amdgcn_mfma_f32_16x16x32_bf16(pa, vb, o[ntd], 0,0,0);
      }
    }
    __builtin_amdgcn_s_setprio(0);
  }

  // ---- epilogue: 1/l in-place (o layout), re-tile through Ps,
  //      16B coalesced stores ----
  const int b = bh / 12, h = bh - b*12;
  #pragma unroll
  for (int v = 0; v < 4; v++) {
    const float invv = 1.0f / l_acc[v];
    const int rl = g*4 + v;                  // 0..15 local row
    #pragma unroll
    for (int ntd = 0; ntd < 4; ntd++) {
      const int cl = ntd*16 + (l & 15);      // 0..63 local col
      Ps[(w*16 + rl)*64 + (((cl >> 3) ^ (rl & 7)) << 3) + (cl & 7)] =
          __float2bfloat16(o[ntd][v] * invv);
    }
  }
  #pragma unroll
  for (int e = 0; e < 2; e++) {
    const int rl = e*8 + (l >> 3);
    const int c  = l & 7;
    uint4 vv = *(const uint4*)&Ps[(w*16 + rl)*64 + ((c ^ (rl & 7)) << 3)];
    const int r = qt*64 + w*16 + rl;
    *(uint4*)&ao[((size_t)(b*1024 + r)) * 768 + h*64 + c*8] = vv;
  }
}

// ---------------------------------------------------------------------------
// Plain MFMA NT-GEMM + bias (proj). global_load_lds staging + XCD swizzle.
// ---------------------------------------------------------------------------
__global__ __launch_bounds__(256) void gemm_mfma(
    const bf16* __restrict__ Ab, const bf16* __restrict__ WT,
    const void* __restrict__ bias, void* __restrict__ Cout,
    const int Nd, const int K, const int c_row_off,
    const int* __restrict__ flag, const int bias_mode, const int c_mode)
{
  const int fl = *flag;
  const bool bbf = (bias_mode == 2) ? (fl != 0) : (bias_mode != 0);
  const bool cbf = (c_mode == 2) ? (fl != 0) : (c_mode != 0);

  __shared__ __align__(16) unsigned short As[128*64];
  __shared__ __align__(16) unsigned short Bs[128*64];

  const int tid = threadIdx.x;
  const int l   = tid & 63;
  const int w   = tid >> 6;
  const int wm  = (w & 1) * 64;
  const int wn  = (w >> 1) * 64;

  const int nwg = gridDim.x * gridDim.y;
  const int bid = blockIdx.y * gridDim.x + blockIdx.x;
  const int lb  = xcd_swizzle(bid, nwg);
  const int gy  = gridDim.y;
  const int brow = lb / gy;
  const int bcol = lb - brow * gy;
  const int row0 = brow * 128;
  const int col0 = bcol * 128;

  const int srow = w*8 + (l >> 3);
  const int sch  = (l & 7) ^ (l >> 3);
  const bf16* Ast = Ab + (size_t)(row0 + srow) * K + sch * 8;
  const bf16* Bst = WT + (size_t)(col0 + srow) * K + sch * 8;

  f32x4 acc[4][4] = {};

  for (int k0 = 0; k0 < K; k0 += 64) {
    __syncthreads();
    #pragma unroll
    for (int i = 0; i < 4; i++) {
      gload16(Ast + (size_t)i*32*K + k0, As + (i*32 + w*8)*64);
      gload16(Bst + (size_t)i*32*K + k0, Bs + (i*32 + w*8)*64);
    }
    __syncthreads();
    #pragma unroll
    for (int s = 0; s < 2; s++) {
      bf16x8 af[4], bg[4];
      const int ch = (s*4 + (l >> 4)) ^ (l & 7);
      #pragma unroll
      for (int i = 0; i < 4; i++) {
        const int rowm = wm + i*16 + (l & 15);
        const int rown = wn + i*16 + (l & 15);
        af[i] = *(const bf16x8*)&As[rowm*64 + ch*8];
        bg[i] = *(const bf16x8*)&Bs[rown*64 + ch*8];
      }
      #pragma unroll
      for (int i = 0; i < 4; i++)
        #pragma unroll
        for (int j = 0; j < 4; j++)
          acc[i][j] = __builtin_amdgcn_mfma_f32_16x16x32_bf16(
                          af[i], bg[j], acc[i][j], 0, 0, 0);
    }
  }

  const int cn    = col0 + wn + (l & 15);
  const int rbase = c_row_off + row0 + wm + (l >> 4) * 4;
  #pragma unroll
  for (int j = 0; j < 4; j++) {
    const int col = cn + j*16;
    const float bval = bbf ? tof(((const bf16*)bias)[col])
                           : ((const float*)bias)[col];
    #pragma unroll
    for (int i = 0; i < 4; i++) {
      #pragma unroll
      for (int v = 0; v < 4; v++) {
        const size_t r = (size_t)(rbase + i*16 + v);
        const float val = acc[i][j][v] + bval;
        if (cbf) ((bf16*)Cout)[r * Nd + col] = __float2bfloat16(val);
        else     ((float*)Cout)[r * Nd + col] = val;
      }
    }
  }
}

// ---------------------------------------------------------------------------
// ws: flag(256B) | WqkvT 3.54MB | WprojT 1.18MB |
//     xb | Qp | Kp | Vt | ao  (each CB*1.57MB)
// ---------------------------------------------------------------------------
extern "C" void kernel_launch(void* const* d_in, const int* in_sizes, int n_in,
                              void* d_out, int out_size, void* d_ws, size_t ws_size,
                              hipStream_t stream)
{
  (void)in_sizes; (void)n_in; (void)out_size;
  const void* x     = d_in[0];
  const void* Wqkv  = d_in[1];
  const void* bqkv  = d_in[2];
  const void* Wproj = d_in[3];
  const void* bproj = d_in[4];
  const int*  pos_h = (const int*)d_in[5];
  const int*  pos_w = (const int*)d_in[6];

  int* flag = (int*)d_ws;
  char* p = (char*)d_ws + 256;
  bf16* WqkvT  = (bf16*)p; p += (size_t)QC_ * C_ * 2;
  bf16* WprojT = (bf16*)p; p += (size_t)C_ * C_ * 2;

  const size_t fixed = 256 + (size_t)QC_*C_*2 + (size_t)C_*C_*2;
  const size_t perb  = 5 * (size_t)N_ * C_ * 2;   // xb,Qp,Kp,Vt,ao per batch
  int CB = 16;
  if (ws_size < fixed + 16*perb) CB = 8;
  if (ws_size < fixed + 8*perb)  CB = 4;
  if (ws_size < fixed + 4*perb)  CB = 2;
  if (ws_size < fixed + 2*perb)  CB = 1;
  const int Mc = CB * N_;
  const size_t tsz = (size_t)Mc * C_;

  bf16* xb  = (bf16*)p;
  bf16* Qp  = xb  + tsz;
  bf16* Kp  = Qp  + tsz;
  bf16* Vtb = Kp  + tsz;
  bf16* ao  = Vtb + tsz;

  detect_dtype<<<1, 256, 0, stream>>>((const unsigned*)x, flag);
  wt_cvt<<<dim3(QC_/32, C_/32), 256, 0, stream>>>(Wqkv, WqkvT, C_, QC_, flag);
  wt_cvt<<<dim3(C_/32,  C_/32), 256, 0, stream>>>(Wproj, WprojT, C_, C_, flag);

  for (int c0 = 0; c0 < B_; c0 += CB) {
    const int n4 = Mc * C_ / 4;
    cvt_x<<<(n4 + 255)/256, 256, 0, stream>>>(x, xb, flag, n4, c0 * N_ * C_ / 4);
    gemm_qkv_rope<<<dim3(Mc/128, QC_/128), 256, 0, stream>>>(
        xb, WqkvT, bqkv, Qp, Kp, Vtb, flag,
        pos_h + (size_t)c0*N_, pos_w + (size_t)c0*N_);
    attn_mfma<<<dim3(N_/64, CB*H_), 256, 0, stream>>>(Qp, Kp, Vtb, ao);
    gemm_mfma<<<dim3(Mc/128, C_/128), 256, 0, stream>>>(
        ao, WprojT, bproj, d_out, C_, C_, c0*N_, flag, 2, 2);
  }
}

// Round 6
// 348.480 us; speedup vs baseline: 2.4588x; 1.0313x over previous
//
#include <hip/hip_runtime.h>
#include <hip/hip_bf16.h>

#define B_ 16
#define N_ 1024
#define C_ 768
#define H_ 12
#define HD_ 64
#define QC_ (3*C_)      // 2304

using bf16 = __hip_bfloat16;
using bf16x8 = __attribute__((ext_vector_type(8))) __bf16;
using f32x4  = __attribute__((ext_vector_type(4))) float;

__device__ __forceinline__ float tof(bf16 v){ return __bfloat162float(v); }

// Async global->LDS 16B DMA. LDS dest is wave-uniform base + lane*16 (linear);
// swizzle is applied on the per-lane GLOBAL address (rule #21).
__device__ __forceinline__ void gload16(const void* g, void* l) {
  __builtin_amdgcn_global_load_lds(
      (const __attribute__((address_space(1))) unsigned int*)g,
      (__attribute__((address_space(3))) unsigned int*)l, 16, 0, 0);
}

// XCD-aware bijective block swizzle (nwg % 8 == 0 holds for all our grids).
__device__ __forceinline__ int xcd_swizzle(int bid, int nwg) {
  return (bid & 7) * (nwg >> 3) + (bid >> 3);
}

// pack two f32 -> one u32 of 2 bf16
__device__ __forceinline__ unsigned pk2(float a, float b) {
  unsigned ua = (unsigned)__bfloat16_as_ushort(__float2bfloat16(a));
  unsigned ub = (unsigned)__bfloat16_as_ushort(__float2bfloat16(b));
  return ua | (ub << 16);
}

// ---------------------------------------------------------------------------
// Input-dtype detector (1=bf16, 0=fp32) from bits 14:7 of sampled words.
// ---------------------------------------------------------------------------
__global__ __launch_bounds__(256) void detect_dtype(
    const unsigned* __restrict__ x32, int* __restrict__ flag)
{
  __shared__ int cnt;
  if (threadIdx.x == 0) cnt = 0;
  __syncthreads();
  int local = 0;
  #pragma unroll
  for (int i = 0; i < 16; i++) {
    unsigned u = x32[threadIdx.x * 16 + i * 4096];
    unsigned e = (u >> 7) & 0xFF;
    local += (e >= 110 && e <= 140) ? 1 : 0;
  }
  atomicAdd(&cnt, local);
  __syncthreads();
  if (threadIdx.x == 0) *flag = (cnt > 2048) ? 1 : 0;
}

// ---------------------------------------------------------------------------
// Cast x (fp32 or bf16 per flag) -> bf16, 4 elems/thread.
// ---------------------------------------------------------------------------
__global__ __launch_bounds__(256) void cvt_x(
    const void* __restrict__ x, bf16* __restrict__ xb,
    const int* __restrict__ flag, const int n4, const int off4)
{
  const int i = blockIdx.x * 256 + threadIdx.x;
  if (i >= n4) return;
  if (*flag) {
    ((uint2*)xb)[i] = ((const uint2*)x)[off4 + i];
  } else {
    float4 v = ((const float4*)x)[off4 + i];
    xb[i*4+0] = __float2bfloat16(v.x);
    xb[i*4+1] = __float2bfloat16(v.y);
    xb[i*4+2] = __float2bfloat16(v.z);
    xb[i*4+3] = __float2bfloat16(v.w);
  }
}

// ---------------------------------------------------------------------------
// WT[n][k] (bf16) = W[k][n] (dtype per flag). Tiled 32x32 transpose.
// ---------------------------------------------------------------------------
__global__ __launch_bounds__(256) void wt_cvt(
    const void* __restrict__ W, bf16* __restrict__ WT,
    const int K, const int Nd, const int* __restrict__ flag)
{
  __shared__ float t[32][33];
  const int fl = *flag;
  const int n0 = blockIdx.x * 32, k0 = blockIdx.y * 32;
  const int tx = threadIdx.x & 31, ty = threadIdx.x >> 5;   // 32 x 8
  for (int kk = ty; kk < 32; kk += 8) {
    const size_t gi = (size_t)(k0 + kk) * Nd + (n0 + tx);
    t[kk][tx] = fl ? tof(((const bf16*)W)[gi]) : ((const float*)W)[gi];
  }
  __syncthreads();
  for (int nn = ty; nn < 32; nn += 8)
    WT[(size_t)(n0 + nn) * K + (k0 + tx)] = __float2bfloat16(t[tx][nn]);
}

// ---------------------------------------------------------------------------
// Fused qkv GEMM + bias + RoPE + layout scatter. (unchanged, verified)
// Q is scaled by 0.125 * log2(e) so attention S arrives in log2 domain.
// ---------------------------------------------------------------------------
__global__ __launch_bounds__(256) void gemm_qkv_rope(
    const bf16* __restrict__ Ab, const bf16* __restrict__ WT,
    const void* __restrict__ bias, bf16* __restrict__ Qp,
    bf16* __restrict__ Kp, bf16* __restrict__ Vtb,
    const int* __restrict__ flag,
    const int* __restrict__ pos_h, const int* __restrict__ pos_w)
{
  const int K = C_;
  const bool bbf = (*flag != 0);

  __shared__ __align__(16) char smem[36864];
  unsigned short* As = (unsigned short*)smem;
  unsigned short* Bs = (unsigned short*)(smem + 16384);

  const int tid = threadIdx.x;
  const int l   = tid & 63;
  const int w   = tid >> 6;
  const int wm  = (w & 1) * 64;
  const int wn  = (w >> 1) * 64;

  const int nwg = gridDim.x * gridDim.y;
  const int bid = blockIdx.y * gridDim.x + blockIdx.x;
  const int lb  = xcd_swizzle(bid, nwg);
  const int gy  = gridDim.y;                 // 18
  const int brow = lb / gy;
  const int bcol = lb - brow * gy;
  const int row0 = brow * 128;
  const int col0 = bcol * 128;

  const int srow = w*8 + (l >> 3);
  const int sch  = (l & 7) ^ (l >> 3);
  const bf16* Ast = Ab + (size_t)(row0 + srow) * K + sch * 8;
  const bf16* Bst = WT + (size_t)(col0 + srow) * K + sch * 8;

  f32x4 acc[4][4] = {};

  for (int k0 = 0; k0 < K; k0 += 64) {
    __syncthreads();                         // prev iter's LDS reads done
    #pragma unroll
    for (int i = 0; i < 4; i++) {
      gload16(Ast + (size_t)i*32*K + k0, As + (i*32 + w*8)*64);
      gload16(Bst + (size_t)i*32*K + k0, Bs + (i*32 + w*8)*64);
    }
    __syncthreads();                         // drains vmcnt -> LDS ready
    #pragma unroll
    for (int s = 0; s < 2; s++) {
      bf16x8 af[4], bg[4];
      const int ch = (s*4 + (l >> 4)) ^ (l & 7);
      #pragma unroll
      for (int i = 0; i < 4; i++) {
        const int rowm = wm + i*16 + (l & 15);
        const int rown = wn + i*16 + (l & 15);
        af[i] = *(const bf16x8*)&As[rowm*64 + ch*8];
        bg[i] = *(const bf16x8*)&Bs[rown*64 + ch*8];
      }
      #pragma unroll
      for (int i = 0; i < 4; i++)
        #pragma unroll
        for (int j = 0; j < 4; j++)
          acc[i][j] = __builtin_amdgcn_mfma_f32_16x16x32_bf16(
                          af[i], bg[j], acc[i][j], 0, 0, 0);
    }
  }

  // ---- fused epilogue ----
  const int colbase = col0 + wn;            // multiple of 64
  const int t   = colbase / 768;            // 0=q 1=k 2=v (block-uniform)
  const int h   = (colbase % 768) >> 6;     // head (wave-uniform)
  const int dd0 = l & 15;
  float bv4[4];
  #pragma unroll
  for (int j = 0; j < 4; j++) {
    const int c = colbase + dd0 + j*16;
    bv4[j] = bbf ? tof(((const bf16*)bias)[c]) : ((const float*)bias)[c];
  }
  const int rb = row0 + wm + (l >> 4) * 4;

  __syncthreads();                           // As/Bs dead for ALL waves
  bf16* Ts = (bf16*)(smem + w * 9216);       // 64 rows x 72 elems (144 B)

  if (t == 2) {
    #pragma unroll
    for (int i = 0; i < 4; i++) {
      #pragma unroll
      for (int v = 0; v < 4; v++) {
        const int nl = i*16 + ((l >> 4) << 2) + v;   // n_local 0..63
        #pragma unroll
        for (int j = 0; j < 4; j++) {
          const int dl = dd0 + j*16;                 // d_local 0..63
          const float y = acc[i][j][v] + bv4[j];
          Ts[dl*72 + (((nl >> 3) ^ (dl & 7)) << 3) + (nl & 7)] =
              __float2bfloat16(y);
        }
      }
    }
  } else {
    const int fi  = dd0 >> 1;
    const float LOG2B = 13.287712379549449f;  // log2(10000)
    const float f1 = exp2f(-LOG2B * (float)fi       * (1.0f/16.0f));
    const float f2 = exp2f(-LOG2B * (float)(fi + 8) * (1.0f/16.0f));
    #pragma unroll
    for (int i = 0; i < 4; i++) {
      #pragma unroll
      for (int v = 0; v < 4; v++) {
        const int r  = rb + i*16 + v;          // chunk-local row (global)
        const int rl = i*16 + (l >> 4)*4 + v;  // row local to wave 0..63
        float y0 = acc[i][0][v] + bv4[0];
        float y1 = acc[i][1][v] + bv4[1];
        float y2 = acc[i][2][v] + bv4[2];
        float y3 = acc[i][3][v] + bv4[3];
        const float ph = (float)pos_h[r];
        const float pw = (float)pos_w[r];
        float s1,c1,s2,c2,s3,c3,s4,c4;
        __sincosf(ph*f1, &s1, &c1);
        __sincosf(ph*f2, &s2, &c2);
        __sincosf(pw*f1, &s3, &c3);
        __sincosf(pw*f2, &s4, &c4);
        float z[4];
        z[0] = y0*c1 - y1*s1;
        z[1] = y1*c2 + y0*s2;
        z[2] = y2*c3 - y3*s3;
        z[3] = y3*c4 + y2*s4;
        if (t == 0) {
          const float QS = 0.18033688011112042f;   // 0.125 * log2(e)
          z[0]*=QS; z[1]*=QS; z[2]*=QS; z[3]*=QS;
        }
        #pragma unroll
        for (int j = 0; j < 4; j++) {
          const int cl = dd0 + j*16;           // col local 0..63
          Ts[rl*72 + (((cl >> 3) ^ (rl & 7)) << 3) + (cl & 7)] =
              __float2bfloat16(z[j]);
        }
      }
    }
  }
  __syncthreads();                           // ds_writes visible (in-block)

  if (t == 2) {
    const int n0 = (row0 + wm) & 1023;
    const int bp = (row0 + wm) >> 10;
    const size_t gbase = (size_t)(bp*12 + h) * 65536;   // [bh][64][1024]
    #pragma unroll
    for (int dr = 0; dr < 8; dr++) {
      const int dl = dr*8 + (l >> 3);
      const int c  = l & 7;                  // logical 8-elem chunk
      uint4 vv = *(const uint4*)&Ts[dl*72 + ((c ^ (dl & 7)) << 3)];
      *(uint4*)&Vtb[gbase + (size_t)dl*1024 + n0 + c*8] = vv;
    }
  } else {
    bf16* dst = (t == 0) ? Qp : Kp;
    const int rg0 = row0 + wm;               // 64-row block, one bp
    const int bp  = rg0 >> 10;
    const int nb  = rg0 & 1023;
    const size_t gbase = (size_t)(bp*12 + h) * 65536;   // [bh][1024][64]
    #pragma unroll
    for (int dr = 0; dr < 8; dr++) {
      const int rl = dr*8 + (l >> 3);
      const int c  = l & 7;
      uint4 vv = *(const uint4*)&Ts[rl*72 + ((c ^ (rl & 7)) << 3)];
      *(uint4*)&dst[gbase + (size_t)(nb + rl)*64 + c*8] = vv;
    }
  }
}

// ---------------------------------------------------------------------------
// MFMA flash attention. Round-6 change: 2-phase double-buffered K/V with
// counted vmcnt (T3-minimum + T4). Loads for tile kt+2 are issued right
// after the post-compute barrier of tile kt; the entry wait is
// s_waitcnt vmcnt(4) (kt+1's 4 DMAs stay in flight) -> load latency hides
// under a full compute phase; vmcnt never drains to 0 in the loop.
// ---------------------------------------------------------------------------
__global__ __launch_bounds__(256) void attn_mfma(
    const bf16* __restrict__ Qp, const bf16* __restrict__ Kp,
    const bf16* __restrict__ Vtb, bf16* __restrict__ ao)
{
  __shared__ __align__(16) bf16 QPs[64*64];     // Qs (prologue) then Ps
  __shared__ __align__(16) bf16 Ks[2][64*64];   // double-buffered K
  __shared__ __align__(16) bf16 Vs[2][64*64];   // double-buffered V^T
  bf16* Qs = QPs;
  bf16* Ps = QPs;
  const int tid = threadIdx.x;
  const int l   = tid & 63;
  const int w   = tid >> 6;

  const int nwg = gridDim.x * gridDim.y;
  const int bid = blockIdx.y * gridDim.x + blockIdx.x;
  const int lb  = xcd_swizzle(bid, nwg);     // bh-major logical order
  const int qt  = lb & 15;                   // 0..15
  const int bh  = lb >> 4;                   // chunk-local b*12 + h
  const size_t base = (size_t)bh * 65536;

  const int srow = w*8 + (l >> 3);
  const int sch  = (l & 7) ^ (l >> 3);
  const bf16* Qst = Qp  + base + (size_t)(qt*64 + srow)*64 + sch*8;
  const bf16* Kst = Kp  + base + (size_t)srow*64   + sch*8;
  const bf16* Vst = Vtb + base + (size_t)srow*1024 + sch*8;

  // stage K/V tile tt into buffer b (4 DMAs per lane-group)
  #define STAGE_KV(tt, b)                                                    \
    { gload16(Kst + (size_t)((tt)*64 +  0)*64, Ks[b] + ( 0 + w*8)*64);       \
      gload16(Kst + (size_t)((tt)*64 + 32)*64, Ks[b] + (32 + w*8)*64);       \
      gload16(Vst + (size_t)(tt)*64,           Vs[b] + ( 0 + w*8)*64);       \
      gload16(Vst + (size_t)32*1024 + (tt)*64, Vs[b] + (32 + w*8)*64); }

  // prologue: Q + tile0 -> full drain (once), read Q frags, stage tile1
  #pragma unroll
  for (int i = 0; i < 2; i++)
    gload16(Qst + (size_t)i*32*64, Qs + (i*32 + w*8)*64);
  STAGE_KV(0, 0);
  __syncthreads();                           // drains vmcnt -> Q + tile0 ready

  bf16x8 af[2];
  {
    const int row = w*16 + (l & 15);
    #pragma unroll
    for (int s = 0; s < 2; s++) {
      const int ch = (s*4 + (l >> 4)) ^ (row & 7);
      af[s] = *(const bf16x8*)&Qs[row*64 + ch*8];
    }
  }
  STAGE_KV(1, 1);                            // tile1 in flight

  bf16x8 ones;
  #pragma unroll
  for (int i = 0; i < 8; i++) ones[i] = (__bf16)1.0f;

  float m_i = -3.0e38f;                      // per-lane, q = w*16 + (l&15)
  f32x4 l_acc = {};                          // denominators, o layout
  f32x4 o[4] = {};                           // q-local=(l>>4)*4+v, d=ntd*16+(l&15)

  const int g    = l >> 4;                   // lane quarter
  const int qrow = w*16 + (l & 15);          // this lane's q-row (local)

  for (int kt = 0; kt < 16; kt++) {
    const int cur = kt & 1;
    if (kt > 0) {
      // tile kt's 4 DMAs done (kt+1's 4 stay in flight); then all-wave sync
      if (kt < 15) { asm volatile("s_waitcnt vmcnt(4)" ::: "memory"); }
      else         { asm volatile("s_waitcnt vmcnt(0)" ::: "memory"); }
      __builtin_amdgcn_s_barrier();
      asm volatile("" ::: "memory");
    }
    const bf16* Ksb = Ks[cur];
    const bf16* Vsb = Vs[cur];

    // ---- S^T = K . Q^T : s[nt][v] = S[k = nt*16 + 4g + v][q = qrow] ----
    f32x4 s[4];
    __builtin_amdgcn_s_setprio(1);
    #pragma unroll
    for (int nt = 0; nt < 4; nt++) {
      f32x4 a = {};
      const int nrow = nt*16 + (l & 15);
      #pragma unroll
      for (int ss = 0; ss < 2; ss++) {
        const int ch = (ss*4 + (l >> 4)) ^ (nrow & 7);
        bf16x8 bg = *(const bf16x8*)&Ksb[nrow*64 + ch*8];
        a = __builtin_amdgcn_mfma_f32_16x16x32_bf16(bg, af[ss], a, 0, 0, 0);
      }
      s[nt] = a;
    }
    __builtin_amdgcn_s_setprio(0);

    // ---- online softmax (log2 domain), per-lane q-row ----
    float a0 = fmaxf(fmaxf(s[0][0], s[0][1]), s[0][2]);
    float a1 = fmaxf(fmaxf(s[0][3], s[1][0]), s[1][1]);
    float a2 = fmaxf(fmaxf(s[1][2], s[1][3]), s[2][0]);
    float a3 = fmaxf(fmaxf(s[2][1], s[2][2]), s[2][3]);
    float a4 = fmaxf(fmaxf(s[3][0], s[3][1]), s[3][2]);
    float b0 = fmaxf(fmaxf(a0, a1), a2);
    float b1 = fmaxf(fmaxf(a3, a4), s[3][3]);
    float mloc = fmaxf(b0, b1);
    mloc = fmaxf(mloc, __shfl_xor(mloc, 16));
    const float m0 = fmaxf(mloc, __shfl_xor(mloc, 32));

    if (!__all(m0 - m_i <= 8.0f)) {          // rescale (rare after tile 0)
      const float mx = fmaxf(m_i, m0);
      const float alpha = exp2f(m_i - mx);
      m_i = mx;
      float a_o[4];
      #pragma unroll
      for (int v = 0; v < 4; v++)            // alpha for o's q-local = 4g+v
        a_o[v] = __shfl(alpha, (l & 48) | ((g << 2) + v));
      #pragma unroll
      for (int v = 0; v < 4; v++) {
        l_acc[v] *= a_o[v];
        #pragma unroll
        for (int nt = 0; nt < 4; nt++) o[nt][v] *= a_o[v];
      }
    }

    // ---- P = 2^(S - m), pack to bf16, b64 store into Ps (wave-private) ----
    #pragma unroll
    for (int nt = 0; nt < 4; nt++) {
      const float p0 = exp2f(s[nt][0] - m_i);
      const float p1 = exp2f(s[nt][1] - m_i);
      const float p2 = exp2f(s[nt][2] - m_i);
      const float p3 = exp2f(s[nt][3] - m_i);
      const int k0 = nt*16 + (g << 2);       // 4 consecutive k
      const int ch = (k0 >> 3) ^ (qrow & 7);
      uint2 uu;
      uu.x = pk2(p0, p1);
      uu.y = pk2(p2, p3);
      *(uint2*)&Ps[qrow*64 + ch*8 + (k0 & 7)] = uu;
    }

    // ---- PV + l: o[q][d] += P[q][k] V^T[d][k]; l_acc += P . 1 ----
    __builtin_amdgcn_s_setprio(1);
    #pragma unroll
    for (int ss = 0; ss < 2; ss++) {
      const int pch  = (ss*4 + g) ^ (qrow & 7);
      bf16x8 pa = *(const bf16x8*)&Ps[qrow*64 + pch*8];
      l_acc = __builtin_amdgcn_mfma_f32_16x16x32_bf16(pa, ones, l_acc, 0,0,0);
      #pragma unroll
      for (int ntd = 0; ntd < 4; ntd++) {
        const int drow = ntd*16 + (l & 15);
        const int vch  = (ss*4 + (l >> 4)) ^ (drow & 7);
        bf16x8 vb = *(const bf16x8*)&Vsb[drow*64 + vch*8];
        o[ntd] = __builtin_amdgcn_mfma_f32_16x16x32_bf16(pa, vb, o[ntd], 0,0,0);
      }
    }
    __builtin_amdgcn_s_setprio(0);

    // all waves done reading buf[cur] -> safe to overwrite it with kt+2
    asm volatile("" ::: "memory");
    __builtin_amdgcn_s_barrier();
    asm volatile("" ::: "memory");
    if (kt + 2 < 16) STAGE_KV(kt + 2, cur);
  }
  #undef STAGE_KV

  // ---- epilogue: 1/l in-place (o layout), re-tile through Ps (wave-
  //      private rows), 16B coalesced stores ----
  const int b = bh / 12, h = bh - b*12;
  #pragma unroll
  for (int v = 0; v < 4; v++) {
    const float invv = 1.0f / l_acc[v];
    const int rl = g*4 + v;                  // 0..15 local row
    #pragma unroll
    for (int ntd = 0; ntd < 4; ntd++) {
      const int cl = ntd*16 + (l & 15);      // 0..63 local col
      Ps[(w*16 + rl)*64 + (((cl >> 3) ^ (rl & 7)) << 3) + (cl & 7)] =
          __float2bfloat16(o[ntd][v] * invv);
    }
  }
  #pragma unroll
  for (int e = 0; e < 2; e++) {
    const int rl = e*8 + (l >> 3);
    const int c  = l & 7;
    uint4 vv = *(const uint4*)&Ps[(w*16 + rl)*64 + ((c ^ (rl & 7)) << 3)];
    const int r = qt*64 + w*16 + rl;
    *(uint4*)&ao[((size_t)(b*1024 + r)) * 768 + h*64 + c*8] = vv;
  }
}

// ---------------------------------------------------------------------------
// Plain MFMA NT-GEMM + bias (proj). global_load_lds staging + XCD swizzle.
// ---------------------------------------------------------------------------
__global__ __launch_bounds__(256) void gemm_mfma(
    const bf16* __restrict__ Ab, const bf16* __restrict__ WT,
    const void* __restrict__ bias, void* __restrict__ Cout,
    const int Nd, const int K, const int c_row_off,
    const int* __restrict__ flag, const int bias_mode, const int c_mode)
{
  const int fl = *flag;
  const bool bbf = (bias_mode == 2) ? (fl != 0) : (bias_mode != 0);
  const bool cbf = (c_mode == 2) ? (fl != 0) : (c_mode != 0);

  __shared__ __align__(16) unsigned short As[128*64];
  __shared__ __align__(16) unsigned short Bs[128*64];

  const int tid = threadIdx.x;
  const int l   = tid & 63;
  const int w   = tid >> 6;
  const int wm  = (w & 1) * 64;
  const int wn  = (w >> 1) * 64;

  const int nwg = gridDim.x * gridDim.y;
  const int bid = blockIdx.y * gridDim.x + blockIdx.x;
  const int lb  = xcd_swizzle(bid, nwg);
  const int gy  = gridDim.y;
  const int brow = lb / gy;
  const int bcol = lb - brow * gy;
  const int row0 = brow * 128;
  const int col0 = bcol * 128;

  const int srow = w*8 + (l >> 3);
  const int sch  = (l & 7) ^ (l >> 3);
  const bf16* Ast = Ab + (size_t)(row0 + srow) * K + sch * 8;
  const bf16* Bst = WT + (size_t)(col0 + srow) * K + sch * 8;

  f32x4 acc[4][4] = {};

  for (int k0 = 0; k0 < K; k0 += 64) {
    __syncthreads();
    #pragma unroll
    for (int i = 0; i < 4; i++) {
      gload16(Ast + (size_t)i*32*K + k0, As + (i*32 + w*8)*64);
      gload16(Bst + (size_t)i*32*K + k0, Bs + (i*32 + w*8)*64);
    }
    __syncthreads();
    #pragma unroll
    for (int s = 0; s < 2; s++) {
      bf16x8 af[4], bg[4];
      const int ch = (s*4 + (l >> 4)) ^ (l & 7);
      #pragma unroll
      for (int i = 0; i < 4; i++) {
        const int rowm = wm + i*16 + (l & 15);
        const int rown = wn + i*16 + (l & 15);
        af[i] = *(const bf16x8*)&As[rowm*64 + ch*8];
        bg[i] = *(const bf16x8*)&Bs[rown*64 + ch*8];
      }
      #pragma unroll
      for (int i = 0; i < 4; i++)
        #pragma unroll
        for (int j = 0; j < 4; j++)
          acc[i][j] = __builtin_amdgcn_mfma_f32_16x16x32_bf16(
                          af[i], bg[j], acc[i][j], 0, 0, 0);
    }
  }

  const int cn    = col0 + wn + (l & 15);
  const int rbase = c_row_off + row0 + wm + (l >> 4) * 4;
  #pragma unroll
  for (int j = 0; j < 4; j++) {
    const int col = cn + j*16;
    const float bval = bbf ? tof(((const bf16*)bias)[col])
                           : ((const float*)bias)[col];
    #pragma unroll
    for (int i = 0; i < 4; i++) {
      #pragma unroll
      for (int v = 0; v < 4; v++) {
        const size_t r = (size_t)(rbase + i*16 + v);
        const float val = acc[i][j][v] + bval;
        if (cbf) ((bf16*)Cout)[r * Nd + col] = __float2bfloat16(val);
        else     ((float*)Cout)[r * Nd + col] = val;
      }
    }
  }
}

// ---------------------------------------------------------------------------
// ws: flag(256B) | WqkvT 3.54MB | WprojT 1.18MB |
//     xb | Qp | Kp | Vt | ao  (each CB*1.57MB)
// ---------------------------------------------------------------------------
extern "C" void kernel_launch(void* const* d_in, const int* in_sizes, int n_in,
                              void* d_out, int out_size, void* d_ws, size_t ws_size,
                              hipStream_t stream)
{
  (void)in_sizes; (void)n_in; (void)out_size;
  const void* x     = d_in[0];
  const void* Wqkv  = d_in[1];
  const void* bqkv  = d_in[2];
  const void* Wproj = d_in[3];
  const void* bproj = d_in[4];
  const int*  pos_h = (const int*)d_in[5];
  const int*  pos_w = (const int*)d_in[6];

  int* flag = (int*)d_ws;
  char* p = (char*)d_ws + 256;
  bf16* WqkvT  = (bf16*)p; p += (size_t)QC_ * C_ * 2;
  bf16* WprojT = (bf16*)p; p += (size_t)C_ * C_ * 2;

  const size_t fixed = 256 + (size_t)QC_*C_*2 + (size_t)C_*C_*2;
  const size_t perb  = 5 * (size_t)N_ * C_ * 2;   // xb,Qp,Kp,Vt,ao per batch
  int CB = 16;
  if (ws_size < fixed + 16*perb) CB = 8;
  if (ws_size < fixed + 8*perb)  CB = 4;
  if (ws_size < fixed + 4*perb)  CB = 2;
  if (ws_size < fixed + 2*perb)  CB = 1;
  const int Mc = CB * N_;
  const size_t tsz = (size_t)Mc * C_;

  bf16* xb  = (bf16*)p;
  bf16* Qp  = xb  + tsz;
  bf16* Kp  = Qp  + tsz;
  bf16* Vtb = Kp  + tsz;
  bf16* ao  = Vtb + tsz;

  detect_dtype<<<1, 256, 0, stream>>>((const unsigned*)x, flag);
  wt_cvt<<<dim3(QC_/32, C_/32), 256, 0, stream>>>(Wqkv, WqkvT, C_, QC_, flag);
  wt_cvt<<<dim3(C_/32,  C_/32), 256, 0, stream>>>(Wproj, WprojT, C_, C_, flag);

  for (int c0 = 0; c0 < B_; c0 += CB) {
    const int n4 = Mc * C_ / 4;
    cvt_x<<<(n4 + 255)/256, 256, 0, stream>>>(x, xb, flag, n4, c0 * N_ * C_ / 4);
    gemm_qkv_rope<<<dim3(Mc/128, QC_/128), 256, 0, stream>>>(
        xb, WqkvT, bqkv, Qp, Kp, Vtb, flag,
        pos_h + (size_t)c0*N_, pos_w + (size_t)c0*N_);
    attn_mfma<<<dim3(N_/64, CB*H_), 256, 0, stream>>>(Qp, Kp, Vtb, ao);
    gemm_mfma<<<dim3(Mc/128, C_/128), 256, 0, stream>>>(
        ao, WprojT, bproj, d_out, C_, C_, c0*N_, flag, 2, 2);
  }
}

// Round 7
// 347.907 us; speedup vs baseline: 2.4629x; 1.0016x over previous
//
#include <hip/hip_runtime.h>
#include <hip/hip_bf16.h>

#define B_ 16
#define N_ 1024
#define C_ 768
#define H_ 12
#define HD_ 64
#define QC_ (3*C_)      // 2304

using bf16 = __hip_bfloat16;
using bf16x8 = __attribute__((ext_vector_type(8))) __bf16;
using f32x4  = __attribute__((ext_vector_type(4))) float;

__device__ __forceinline__ float tof(bf16 v){ return __bfloat162float(v); }

// Async global->LDS 16B DMA. LDS dest is wave-uniform base + lane*16 (linear);
// swizzle is applied on the per-lane GLOBAL address (rule #21).
__device__ __forceinline__ void gload16(const void* g, void* l) {
  __builtin_amdgcn_global_load_lds(
      (const __attribute__((address_space(1))) unsigned int*)g,
      (__attribute__((address_space(3))) unsigned int*)l, 16, 0, 0);
}

// XCD-aware bijective block swizzle (nwg % 8 == 0 holds for all our grids).
__device__ __forceinline__ int xcd_swizzle(int bid, int nwg) {
  return (bid & 7) * (nwg >> 3) + (bid >> 3);
}

// pack two f32 -> one u32 of 2 bf16
__device__ __forceinline__ unsigned pk2(float a, float b) {
  unsigned ua = (unsigned)__bfloat16_as_ushort(__float2bfloat16(a));
  unsigned ub = (unsigned)__bfloat16_as_ushort(__float2bfloat16(b));
  return ua | (ub << 16);
}

// ---------------------------------------------------------------------------
// Input-dtype detector (1=bf16, 0=fp32) from bits 14:7 of sampled words.
// ---------------------------------------------------------------------------
__global__ __launch_bounds__(256) void detect_dtype(
    const unsigned* __restrict__ x32, int* __restrict__ flag)
{
  __shared__ int cnt;
  if (threadIdx.x == 0) cnt = 0;
  __syncthreads();
  int local = 0;
  #pragma unroll
  for (int i = 0; i < 16; i++) {
    unsigned u = x32[threadIdx.x * 16 + i * 4096];
    unsigned e = (u >> 7) & 0xFF;
    local += (e >= 110 && e <= 140) ? 1 : 0;
  }
  atomicAdd(&cnt, local);
  __syncthreads();
  if (threadIdx.x == 0) *flag = (cnt > 2048) ? 1 : 0;
}

// ---------------------------------------------------------------------------
// Cast x (fp32 or bf16 per flag) -> bf16, 4 elems/thread.
// ---------------------------------------------------------------------------
__global__ __launch_bounds__(256) void cvt_x(
    const void* __restrict__ x, bf16* __restrict__ xb,
    const int* __restrict__ flag, const int n4, const int off4)
{
  const int i = blockIdx.x * 256 + threadIdx.x;
  if (i >= n4) return;
  if (*flag) {
    ((uint2*)xb)[i] = ((const uint2*)x)[off4 + i];
  } else {
    float4 v = ((const float4*)x)[off4 + i];
    xb[i*4+0] = __float2bfloat16(v.x);
    xb[i*4+1] = __float2bfloat16(v.y);
    xb[i*4+2] = __float2bfloat16(v.z);
    xb[i*4+3] = __float2bfloat16(v.w);
  }
}

// ---------------------------------------------------------------------------
// WT[n][k] (bf16) = W[k][n] (dtype per flag). Tiled 32x32 transpose.
// ---------------------------------------------------------------------------
__global__ __launch_bounds__(256) void wt_cvt(
    const void* __restrict__ W, bf16* __restrict__ WT,
    const int K, const int Nd, const int* __restrict__ flag)
{
  __shared__ float t[32][33];
  const int fl = *flag;
  const int n0 = blockIdx.x * 32, k0 = blockIdx.y * 32;
  const int tx = threadIdx.x & 31, ty = threadIdx.x >> 5;   // 32 x 8
  for (int kk = ty; kk < 32; kk += 8) {
    const size_t gi = (size_t)(k0 + kk) * Nd + (n0 + tx);
    t[kk][tx] = fl ? tof(((const bf16*)W)[gi]) : ((const float*)W)[gi];
  }
  __syncthreads();
  for (int nn = ty; nn < 32; nn += 8)
    WT[(size_t)(n0 + nn) * K + (k0 + tx)] = __float2bfloat16(t[tx][nn]);
}

// ---------------------------------------------------------------------------
// Fused qkv GEMM + bias + RoPE + layout scatter. (unchanged, verified)
// Q is scaled by 0.125 * log2(e) so attention S arrives in log2 domain.
// ---------------------------------------------------------------------------
__global__ __launch_bounds__(256) void gemm_qkv_rope(
    const bf16* __restrict__ Ab, const bf16* __restrict__ WT,
    const void* __restrict__ bias, bf16* __restrict__ Qp,
    bf16* __restrict__ Kp, bf16* __restrict__ Vtb,
    const int* __restrict__ flag,
    const int* __restrict__ pos_h, const int* __restrict__ pos_w)
{
  const int K = C_;
  const bool bbf = (*flag != 0);

  __shared__ __align__(16) char smem[36864];
  unsigned short* As = (unsigned short*)smem;
  unsigned short* Bs = (unsigned short*)(smem + 16384);

  const int tid = threadIdx.x;
  const int l   = tid & 63;
  const int w   = tid >> 6;
  const int wm  = (w & 1) * 64;
  const int wn  = (w >> 1) * 64;

  const int nwg = gridDim.x * gridDim.y;
  const int bid = blockIdx.y * gridDim.x + blockIdx.x;
  const int lb  = xcd_swizzle(bid, nwg);
  const int gy  = gridDim.y;                 // 18
  const int brow = lb / gy;
  const int bcol = lb - brow * gy;
  const int row0 = brow * 128;
  const int col0 = bcol * 128;

  const int srow = w*8 + (l >> 3);
  const int sch  = (l & 7) ^ (l >> 3);
  const bf16* Ast = Ab + (size_t)(row0 + srow) * K + sch * 8;
  const bf16* Bst = WT + (size_t)(col0 + srow) * K + sch * 8;

  f32x4 acc[4][4] = {};

  for (int k0 = 0; k0 < K; k0 += 64) {
    __syncthreads();                         // prev iter's LDS reads done
    #pragma unroll
    for (int i = 0; i < 4; i++) {
      gload16(Ast + (size_t)i*32*K + k0, As + (i*32 + w*8)*64);
      gload16(Bst + (size_t)i*32*K + k0, Bs + (i*32 + w*8)*64);
    }
    __syncthreads();                         // drains vmcnt -> LDS ready
    #pragma unroll
    for (int s = 0; s < 2; s++) {
      bf16x8 af[4], bg[4];
      const int ch = (s*4 + (l >> 4)) ^ (l & 7);
      #pragma unroll
      for (int i = 0; i < 4; i++) {
        const int rowm = wm + i*16 + (l & 15);
        const int rown = wn + i*16 + (l & 15);
        af[i] = *(const bf16x8*)&As[rowm*64 + ch*8];
        bg[i] = *(const bf16x8*)&Bs[rown*64 + ch*8];
      }
      #pragma unroll
      for (int i = 0; i < 4; i++)
        #pragma unroll
        for (int j = 0; j < 4; j++)
          acc[i][j] = __builtin_amdgcn_mfma_f32_16x16x32_bf16(
                          af[i], bg[j], acc[i][j], 0, 0, 0);
    }
  }

  // ---- fused epilogue ----
  const int colbase = col0 + wn;            // multiple of 64
  const int t   = colbase / 768;            // 0=q 1=k 2=v (block-uniform)
  const int h   = (colbase % 768) >> 6;     // head (wave-uniform)
  const int dd0 = l & 15;
  float bv4[4];
  #pragma unroll
  for (int j = 0; j < 4; j++) {
    const int c = colbase + dd0 + j*16;
    bv4[j] = bbf ? tof(((const bf16*)bias)[c]) : ((const float*)bias)[c];
  }
  const int rb = row0 + wm + (l >> 4) * 4;

  __syncthreads();                           // As/Bs dead for ALL waves
  bf16* Ts = (bf16*)(smem + w * 9216);       // 64 rows x 72 elems (144 B)

  if (t == 2) {
    #pragma unroll
    for (int i = 0; i < 4; i++) {
      #pragma unroll
      for (int v = 0; v < 4; v++) {
        const int nl = i*16 + ((l >> 4) << 2) + v;   // n_local 0..63
        #pragma unroll
        for (int j = 0; j < 4; j++) {
          const int dl = dd0 + j*16;                 // d_local 0..63
          const float y = acc[i][j][v] + bv4[j];
          Ts[dl*72 + (((nl >> 3) ^ (dl & 7)) << 3) + (nl & 7)] =
              __float2bfloat16(y);
        }
      }
    }
  } else {
    const int fi  = dd0 >> 1;
    const float LOG2B = 13.287712379549449f;  // log2(10000)
    const float f1 = exp2f(-LOG2B * (float)fi       * (1.0f/16.0f));
    const float f2 = exp2f(-LOG2B * (float)(fi + 8) * (1.0f/16.0f));
    #pragma unroll
    for (int i = 0; i < 4; i++) {
      #pragma unroll
      for (int v = 0; v < 4; v++) {
        const int r  = rb + i*16 + v;          // chunk-local row (global)
        const int rl = i*16 + (l >> 4)*4 + v;  // row local to wave 0..63
        float y0 = acc[i][0][v] + bv4[0];
        float y1 = acc[i][1][v] + bv4[1];
        float y2 = acc[i][2][v] + bv4[2];
        float y3 = acc[i][3][v] + bv4[3];
        const float ph = (float)pos_h[r];
        const float pw = (float)pos_w[r];
        float s1,c1,s2,c2,s3,c3,s4,c4;
        __sincosf(ph*f1, &s1, &c1);
        __sincosf(ph*f2, &s2, &c2);
        __sincosf(pw*f1, &s3, &c3);
        __sincosf(pw*f2, &s4, &c4);
        float z[4];
        z[0] = y0*c1 - y1*s1;
        z[1] = y1*c2 + y0*s2;
        z[2] = y2*c3 - y3*s3;
        z[3] = y3*c4 + y2*s4;
        if (t == 0) {
          const float QS = 0.18033688011112042f;   // 0.125 * log2(e)
          z[0]*=QS; z[1]*=QS; z[2]*=QS; z[3]*=QS;
        }
        #pragma unroll
        for (int j = 0; j < 4; j++) {
          const int cl = dd0 + j*16;           // col local 0..63
          Ts[rl*72 + (((cl >> 3) ^ (rl & 7)) << 3) + (cl & 7)] =
              __float2bfloat16(z[j]);
        }
      }
    }
  }
  __syncthreads();                           // ds_writes visible (in-block)

  if (t == 2) {
    const int n0 = (row0 + wm) & 1023;
    const int bp = (row0 + wm) >> 10;
    const size_t gbase = (size_t)(bp*12 + h) * 65536;   // [bh][64][1024]
    #pragma unroll
    for (int dr = 0; dr < 8; dr++) {
      const int dl = dr*8 + (l >> 3);
      const int c  = l & 7;                  // logical 8-elem chunk
      uint4 vv = *(const uint4*)&Ts[dl*72 + ((c ^ (dl & 7)) << 3)];
      *(uint4*)&Vtb[gbase + (size_t)dl*1024 + n0 + c*8] = vv;
    }
  } else {
    bf16* dst = (t == 0) ? Qp : Kp;
    const int rg0 = row0 + wm;               // 64-row block, one bp
    const int bp  = rg0 >> 10;
    const int nb  = rg0 & 1023;
    const size_t gbase = (size_t)(bp*12 + h) * 65536;   // [bh][1024][64]
    #pragma unroll
    for (int dr = 0; dr < 8; dr++) {
      const int rl = dr*8 + (l >> 3);
      const int c  = l & 7;
      uint4 vv = *(const uint4*)&Ts[rl*72 + ((c ^ (rl & 7)) << 3)];
      *(uint4*)&dst[gbase + (size_t)(nb + rl)*64 + c*8] = vv;
    }
  }
}

// ---------------------------------------------------------------------------
// MFMA flash attention. Round-7: 512-thread blocks (8 waves), q-tile 128.
//  * per-wave work identical (16 q-rows/wave); K/V staging DMAs halve
//    (8 waves share the 64-row tile: 1 K + 1 V DMA per wave per tile).
//  * LDS 48 KB/block -> 3 blocks/CU = 24 waves/CU (75% occupancy, was 38%)
//    -> 6 waves/SIMD to hide the softmax dependent chain.
//  * 2-phase double-buffer + counted vmcnt(2) retained.
// ---------------------------------------------------------------------------
__global__ __launch_bounds__(512) void attn_mfma(
    const bf16* __restrict__ Qp, const bf16* __restrict__ Kp,
    const bf16* __restrict__ Vtb, bf16* __restrict__ ao)
{
  __shared__ __align__(16) bf16 QPs[128*64];    // Qs (prologue) then Ps
  __shared__ __align__(16) bf16 Ks[2][64*64];   // double-buffered K
  __shared__ __align__(16) bf16 Vs[2][64*64];   // double-buffered V^T
  bf16* Qs = QPs;
  bf16* Ps = QPs;
  const int tid = threadIdx.x;
  const int l   = tid & 63;
  const int w   = tid >> 6;                  // 0..7

  const int nwg = gridDim.x * gridDim.y;
  const int bid = blockIdx.y * gridDim.x + blockIdx.x;
  const int lb  = xcd_swizzle(bid, nwg);     // bh-major logical order
  const int qt  = lb & 7;                    // 0..7 (128-row q tiles)
  const int bh  = lb >> 3;                   // chunk-local b*12 + h
  const size_t base = (size_t)bh * 65536;

  const int srow = w*8 + (l >> 3);           // 0..63 across 8 waves
  const int sch  = (l & 7) ^ (l >> 3);
  const bf16* Qst = Qp  + base + (size_t)(qt*128 + srow)*64 + sch*8;
  const bf16* Kst = Kp  + base + (size_t)srow*64   + sch*8;
  const bf16* Vst = Vtb + base + (size_t)srow*1024 + sch*8;

  // stage K/V tile tt into buffer b: ONE K DMA + ONE V DMA per wave
  #define STAGE_KV(tt, b)                                                    \
    { gload16(Kst + (size_t)(tt)*64*64, Ks[b] + (w*8)*64);                   \
      gload16(Vst + (size_t)(tt)*64,    Vs[b] + (w*8)*64); }

  // prologue: Q (2 DMAs/wave, 128 rows) + tile0 -> full drain, read Q frags,
  // stage tile1
  #pragma unroll
  for (int i = 0; i < 2; i++)
    gload16(Qst + (size_t)i*64*64, Qs + (i*64 + w*8)*64);
  STAGE_KV(0, 0);
  __syncthreads();                           // drains vmcnt -> Q + tile0 ready

  bf16x8 af[2];
  {
    const int row = w*16 + (l & 15);         // 0..127
    #pragma unroll
    for (int s = 0; s < 2; s++) {
      const int ch = (s*4 + (l >> 4)) ^ (row & 7);
      af[s] = *(const bf16x8*)&Qs[row*64 + ch*8];
    }
  }
  STAGE_KV(1, 1);                            // tile1 in flight (2 DMAs)

  bf16x8 ones;
  #pragma unroll
  for (int i = 0; i < 8; i++) ones[i] = (__bf16)1.0f;

  float m_i = -3.0e38f;                      // per-lane, q = w*16 + (l&15)
  f32x4 l_acc = {};                          // denominators, o layout
  f32x4 o[4] = {};                           // q-local=(l>>4)*4+v, d=ntd*16+(l&15)

  const int g    = l >> 4;                   // lane quarter
  const int qrow = w*16 + (l & 15);          // this lane's q-row (local)

  for (int kt = 0; kt < 16; kt++) {
    const int cur = kt & 1;
    if (kt > 0) {
      // tile kt's 2 DMAs done (kt+1's 2 stay in flight); then all-wave sync
      if (kt < 15) { asm volatile("s_waitcnt vmcnt(2)" ::: "memory"); }
      else         { asm volatile("s_waitcnt vmcnt(0)" ::: "memory"); }
      __builtin_amdgcn_s_barrier();
      asm volatile("" ::: "memory");
    }
    const bf16* Ksb = Ks[cur];
    const bf16* Vsb = Vs[cur];

    // ---- S^T = K . Q^T : s[nt][v] = S[k = nt*16 + 4g + v][q = qrow] ----
    f32x4 s[4];
    __builtin_amdgcn_s_setprio(1);
    #pragma unroll
    for (int nt = 0; nt < 4; nt++) {
      f32x4 a = {};
      const int nrow = nt*16 + (l & 15);
      #pragma unroll
      for (int ss = 0; ss < 2; ss++) {
        const int ch = (ss*4 + (l >> 4)) ^ (nrow & 7);
        bf16x8 bg = *(const bf16x8*)&Ksb[nrow*64 + ch*8];
        a = __builtin_amdgcn_mfma_f32_16x16x32_bf16(bg, af[ss], a, 0, 0, 0);
      }
      s[nt] = a;
    }
    __builtin_amdgcn_s_setprio(0);

    // ---- online softmax (log2 domain), per-lane q-row ----
    float a0 = fmaxf(fmaxf(s[0][0], s[0][1]), s[0][2]);
    float a1 = fmaxf(fmaxf(s[0][3], s[1][0]), s[1][1]);
    float a2 = fmaxf(fmaxf(s[1][2], s[1][3]), s[2][0]);
    float a3 = fmaxf(fmaxf(s[2][1], s[2][2]), s[2][3]);
    float a4 = fmaxf(fmaxf(s[3][0], s[3][1]), s[3][2]);
    float b0 = fmaxf(fmaxf(a0, a1), a2);
    float b1 = fmaxf(fmaxf(a3, a4), s[3][3]);
    float mloc = fmaxf(b0, b1);
    mloc = fmaxf(mloc, __shfl_xor(mloc, 16));
    const float m0 = fmaxf(mloc, __shfl_xor(mloc, 32));

    if (!__all(m0 - m_i <= 8.0f)) {          // rescale (rare after tile 0)
      const float mx = fmaxf(m_i, m0);
      const float alpha = exp2f(m_i - mx);
      m_i = mx;
      float a_o[4];
      #pragma unroll
      for (int v = 0; v < 4; v++)            // alpha for o's q-local = 4g+v
        a_o[v] = __shfl(alpha, (l & 48) | ((g << 2) + v));
      #pragma unroll
      for (int v = 0; v < 4; v++) {
        l_acc[v] *= a_o[v];
        #pragma unroll
        for (int nt = 0; nt < 4; nt++) o[nt][v] *= a_o[v];
      }
    }

    // ---- P = 2^(S - m), pack to bf16, b64 store into Ps (wave-private) ----
    #pragma unroll
    for (int nt = 0; nt < 4; nt++) {
      const float p0 = exp2f(s[nt][0] - m_i);
      const float p1 = exp2f(s[nt][1] - m_i);
      const float p2 = exp2f(s[nt][2] - m_i);
      const float p3 = exp2f(s[nt][3] - m_i);
      const int k0 = nt*16 + (g << 2);       // 4 consecutive k
      const int ch = (k0 >> 3) ^ (qrow & 7);
      uint2 uu;
      uu.x = pk2(p0, p1);
      uu.y = pk2(p2, p3);
      *(uint2*)&Ps[qrow*64 + ch*8 + (k0 & 7)] = uu;
    }

    // ---- PV + l: o[q][d] += P[q][k] V^T[d][k]; l_acc += P . 1 ----
    __builtin_amdgcn_s_setprio(1);
    #pragma unroll
    for (int ss = 0; ss < 2; ss++) {
      const int pch  = (ss*4 + g) ^ (qrow & 7);
      bf16x8 pa = *(const bf16x8*)&Ps[qrow*64 + pch*8];
      l_acc = __builtin_amdgcn_mfma_f32_16x16x32_bf16(pa, ones, l_acc, 0,0,0);
      #pragma unroll
      for (int ntd = 0; ntd < 4; ntd++) {
        const int drow = ntd*16 + (l & 15);
        const int vch  = (ss*4 + (l >> 4)) ^ (drow & 7);
        bf16x8 vb = *(const bf16x8*)&Vsb[drow*64 + vch*8];
        o[ntd] = __builtin_amdgcn_mfma_f32_16x16x32_bf16(pa, vb, o[ntd], 0,0,0);
      }
    }
    __builtin_amdgcn_s_setprio(0);

    // all waves done reading buf[cur] -> safe to overwrite it with kt+2
    asm volatile("" ::: "memory");
    __builtin_amdgcn_s_barrier();
    asm volatile("" ::: "memory");
    if (kt + 2 < 16) STAGE_KV(kt + 2, cur);
  }
  #undef STAGE_KV

  // ---- epilogue: 1/l in-place (o layout), re-tile through Ps (wave-
  //      private rows), 16B coalesced stores ----
  const int b = bh / 12, h = bh - b*12;
  #pragma unroll
  for (int v = 0; v < 4; v++) {
    const float invv = 1.0f / l_acc[v];
    const int rl = g*4 + v;                  // 0..15 local row
    #pragma unroll
    for (int ntd = 0; ntd < 4; ntd++) {
      const int cl = ntd*16 + (l & 15);      // 0..63 local col
      Ps[(w*16 + rl)*64 + (((cl >> 3) ^ (rl & 7)) << 3) + (cl & 7)] =
          __float2bfloat16(o[ntd][v] * invv);
    }
  }
  #pragma unroll
  for (int e = 0; e < 2; e++) {
    const int rl = e*8 + (l >> 3);
    const int c  = l & 7;
    uint4 vv = *(const uint4*)&Ps[(w*16 + rl)*64 + ((c ^ (rl & 7)) << 3)];
    const int r = qt*128 + w*16 + rl;
    *(uint4*)&ao[((size_t)(b*1024 + r)) * 768 + h*64 + c*8] = vv;
  }
}

// ---------------------------------------------------------------------------
// Plain MFMA NT-GEMM + bias (proj). global_load_lds staging + XCD swizzle.
// ---------------------------------------------------------------------------
__global__ __launch_bounds__(256) void gemm_mfma(
    const bf16* __restrict__ Ab, const bf16* __restrict__ WT,
    const void* __restrict__ bias, void* __restrict__ Cout,
    const int Nd, const int K, const int c_row_off,
    const int* __restrict__ flag, const int bias_mode, const int c_mode)
{
  const int fl = *flag;
  const bool bbf = (bias_mode == 2) ? (fl != 0) : (bias_mode != 0);
  const bool cbf = (c_mode == 2) ? (fl != 0) : (c_mode != 0);

  __shared__ __align__(16) unsigned short As[128*64];
  __shared__ __align__(16) unsigned short Bs[128*64];

  const int tid = threadIdx.x;
  const int l   = tid & 63;
  const int w   = tid >> 6;
  const int wm  = (w & 1) * 64;
  const int wn  = (w >> 1) * 64;

  const int nwg = gridDim.x * gridDim.y;
  const int bid = blockIdx.y * gridDim.x + blockIdx.x;
  const int lb  = xcd_swizzle(bid, nwg);
  const int gy  = gridDim.y;
  const int brow = lb / gy;
  const int bcol = lb - brow * gy;
  const int row0 = brow * 128;
  const int col0 = bcol * 128;

  const int srow = w*8 + (l >> 3);
  const int sch  = (l & 7) ^ (l >> 3);
  const bf16* Ast = Ab + (size_t)(row0 + srow) * K + sch * 8;
  const bf16* Bst = WT + (size_t)(col0 + srow) * K + sch * 8;

  f32x4 acc[4][4] = {};

  for (int k0 = 0; k0 < K; k0 += 64) {
    __syncthreads();
    #pragma unroll
    for (int i = 0; i < 4; i++) {
      gload16(Ast + (size_t)i*32*K + k0, As + (i*32 + w*8)*64);
      gload16(Bst + (size_t)i*32*K + k0, Bs + (i*32 + w*8)*64);
    }
    __syncthreads();
    #pragma unroll
    for (int s = 0; s < 2; s++) {
      bf16x8 af[4], bg[4];
      const int ch = (s*4 + (l >> 4)) ^ (l & 7);
      #pragma unroll
      for (int i = 0; i < 4; i++) {
        const int rowm = wm + i*16 + (l & 15);
        const int rown = wn + i*16 + (l & 15);
        af[i] = *(const bf16x8*)&As[rowm*64 + ch*8];
        bg[i] = *(const bf16x8*)&Bs[rown*64 + ch*8];
      }
      #pragma unroll
      for (int i = 0; i < 4; i++)
        #pragma unroll
        for (int j = 0; j < 4; j++)
          acc[i][j] = __builtin_amdgcn_mfma_f32_16x16x32_bf16(
                          af[i], bg[j], acc[i][j], 0, 0, 0);
    }
  }

  const int cn    = col0 + wn + (l & 15);
  const int rbase = c_row_off + row0 + wm + (l >> 4) * 4;
  #pragma unroll
  for (int j = 0; j < 4; j++) {
    const int col = cn + j*16;
    const float bval = bbf ? tof(((const bf16*)bias)[col])
                           : ((const float*)bias)[col];
    #pragma unroll
    for (int i = 0; i < 4; i++) {
      #pragma unroll
      for (int v = 0; v < 4; v++) {
        const size_t r = (size_t)(rbase + i*16 + v);
        const float val = acc[i][j][v] + bval;
        if (cbf) ((bf16*)Cout)[r * Nd + col] = __float2bfloat16(val);
        else     ((float*)Cout)[r * Nd + col] = val;
      }
    }
  }
}

// ---------------------------------------------------------------------------
// ws: flag(256B) | WqkvT 3.54MB | WprojT 1.18MB |
//     xb | Qp | Kp | Vt | ao  (each CB*1.57MB)
// ---------------------------------------------------------------------------
extern "C" void kernel_launch(void* const* d_in, const int* in_sizes, int n_in,
                              void* d_out, int out_size, void* d_ws, size_t ws_size,
                              hipStream_t stream)
{
  (void)in_sizes; (void)n_in; (void)out_size;
  const void* x     = d_in[0];
  const void* Wqkv  = d_in[1];
  const void* bqkv  = d_in[2];
  const void* Wproj = d_in[3];
  const void* bproj = d_in[4];
  const int*  pos_h = (const int*)d_in[5];
  const int*  pos_w = (const int*)d_in[6];

  int* flag = (int*)d_ws;
  char* p = (char*)d_ws + 256;
  bf16* WqkvT  = (bf16*)p; p += (size_t)QC_ * C_ * 2;
  bf16* WprojT = (bf16*)p; p += (size_t)C_ * C_ * 2;

  const size_t fixed = 256 + (size_t)QC_*C_*2 + (size_t)C_*C_*2;
  const size_t perb  = 5 * (size_t)N_ * C_ * 2;   // xb,Qp,Kp,Vt,ao per batch
  int CB = 16;
  if (ws_size < fixed + 16*perb) CB = 8;
  if (ws_size < fixed + 8*perb)  CB = 4;
  if (ws_size < fixed + 4*perb)  CB = 2;
  if (ws_size < fixed + 2*perb)  CB = 1;
  const int Mc = CB * N_;
  const size_t tsz = (size_t)Mc * C_;

  bf16* xb  = (bf16*)p;
  bf16* Qp  = xb  + tsz;
  bf16* Kp  = Qp  + tsz;
  bf16* Vtb = Kp  + tsz;
  bf16* ao  = Vtb + tsz;

  detect_dtype<<<1, 256, 0, stream>>>((const unsigned*)x, flag);
  wt_cvt<<<dim3(QC_/32, C_/32), 256, 0, stream>>>(Wqkv, WqkvT, C_, QC_, flag);
  wt_cvt<<<dim3(C_/32,  C_/32), 256, 0, stream>>>(Wproj, WprojT, C_, C_, flag);

  for (int c0 = 0; c0 < B_; c0 += CB) {
    const int n4 = Mc * C_ / 4;
    cvt_x<<<(n4 + 255)/256, 256, 0, stream>>>(x, xb, flag, n4, c0 * N_ * C_ / 4);
    gemm_qkv_rope<<<dim3(Mc/128, QC_/128), 256, 0, stream>>>(
        xb, WqkvT, bqkv, Qp, Kp, Vtb, flag,
        pos_h + (size_t)c0*N_, pos_w + (size_t)c0*N_);
    attn_mfma<<<dim3(N_/128, CB*H_), 512, 0, stream>>>(Qp, Kp, Vtb, ao);
    gemm_mfma<<<dim3(Mc/128, C_/128), 256, 0, stream>>>(
        ao, WprojT, bproj, d_out, C_, C_, c0*N_, flag, 2, 2);
  }
}